// Round 9
// baseline (427.623 us; speedup 1.0000x reference)
//
#include <hip/hip_runtime.h>
#include <hip/hip_bf16.h>

typedef __bf16 bf16;
typedef __bf16 bf16x4 __attribute__((ext_vector_type(4)));
typedef __bf16 bf16x8 __attribute__((ext_vector_type(8)));
typedef float f32x4 __attribute__((ext_vector_type(4)));

#define DIM 768
#define HW 1024          // 32*32
#define BATCH 16
#define M_TOTAL (BATCH * HW)   // 16384
#define NKT 24                 // K-steps of 32

// ======================== k-permutation convention =========================
// All bf16 [.][768] activation buffers and Wb[768][768] store the k (channel)
// dimension permuted within each 32-group: physical position p = 8g+j holds
// logical k = 4g+j (j<4) or 16+4g+(j-4) (j>=4). mfma_f32_16x16x32_bf16
// fragments are then CONTIGUOUS 16B in memory -> one global_load_dwordx4
// per fragment, no LDS needed. k2pos(kk) = (((kk&15)>>2)<<3)+(kk&3)+((kk>>4)<<2).

// ------------- prep: weights f32->bf16 k-permuted + x NCHW -> [n][c] bf16 -------------
__global__ void prep_kernel(const float* __restrict__ x, bf16* __restrict__ xb,
                            const float4* __restrict__ w1, const float4* __restrict__ w2,
                            const float4* __restrict__ w3,
                            bf16x8* __restrict__ o1, bf16x8* __restrict__ o2,
                            bf16x8* __restrict__ o3) {
    __shared__ float tile[32][33];
    if (blockIdx.x < 864) {
        const int b = blockIdx.x;
        const int which = b / 288;
        const int i = (b % 288) * 256 + threadIdx.x;
        const float4* w = which == 0 ? w1 : which == 1 ? w2 : w3;
        bf16x8* o = which == 0 ? o1 : which == 1 ? o2 : o3;
        const int row = i / 96, br = i % 96;
        const int q = br >> 2, g = br & 3;
        float4 lo = w[row * 192 + q * 8 + g];
        float4 hi = w[row * 192 + q * 8 + g + 4];
        bf16x8 r = { (bf16)lo.x, (bf16)lo.y, (bf16)lo.z, (bf16)lo.w,
                     (bf16)hi.x, (bf16)hi.y, (bf16)hi.z, (bf16)hi.w };
        o[row * 96 + br] = r;
    } else {
        const int e = blockIdx.x - 864;
        const int b = e / 768;
        const int rem = e % 768;
        const int c0 = (rem / 32) * 32;
        const int hw0 = (rem % 32) * 32;
        const int tx = threadIdx.x & 31, ty = threadIdx.x >> 5;  // 32 x 8

        const float* src = x + ((size_t)b * DIM + c0) * HW + hw0;
#pragma unroll
        for (int j = 0; j < 4; j++)
            tile[ty + 8 * j][tx] = src[(size_t)(ty + 8 * j) * HW + tx];
        __syncthreads();
        const int ptx = (((tx & 15) >> 2) << 3) + (tx & 3) + ((tx >> 4) << 2);  // k2pos
        bf16* dst = xb + ((size_t)b * HW + hw0) * DIM + c0;
#pragma unroll
        for (int j = 0; j < 4; j++)
            dst[(size_t)(ty + 8 * j) * DIM + ptx] = (bf16)tile[tx][ty + 8 * j];
    }
}

// ---------------- flatmm GEMM: C[M][768] = A[M][768] * W^T (+bias) ----------------
// NO LDS, NO barriers: k-permuted layout makes every MFMA fragment a
// contiguous 16B global load (wave = 16 rows x 64B = 16 full lines).
// BM=64, BN=192, 4 waves (2x2, wave-tile 32x96), grid 1024 = 4 blocks/CU.
// Per wave K-step: 8 frag loads (next) || 12 MFMA (cur), register dbuf;
// compiler inserts counted vmcnt. W is L2-resident; A/B frag redundancy (2x
// within block) served by L1. Accumulators live in AGPRs.
// MODE 0: write bf16 [n][768] k-permuted (+bias). MODE 1: f32 NCHW (+bias).
template <int MODE>
__global__ __launch_bounds__(256, 4) void gemm_kernel(
    const bf16* __restrict__ A,    // [M][768] k-permuted
    const bf16* __restrict__ Bw,   // [768][768] rows linear, cols k-permuted
    const float* __restrict__ bias,
    void* __restrict__ out)
{
    const int t = threadIdx.x;
    const int lane = t & 63;
    const int wave = t >> 6;
    const int wm = wave >> 1, wn = wave & 1;   // 2x2 -> wave tile 32x96

    // grid 1024 = 8 XCD chunks of 128; n fastest (4 n-tiles share A-panel,
    // each XCD owns a contiguous 32-m-tile band -> A L2-local).
    const int bid = blockIdx.x;
    const int virt = (bid & 7) * 128 + (bid >> 3);
    const int m0 = (virt >> 2) * 64;
    const int n0 = (virt & 3) * 192;

    const int fr = lane & 15, fq = lane >> 4;

    // int32 element offsets; frag for K-step kt sits at +kt*32 elems
    int aOff[2], bOff[6];
#pragma unroll
    for (int mi = 0; mi < 2; mi++)
        aOff[mi] = (m0 + wm * 32 + mi * 16 + fr) * DIM + fq * 8;
#pragma unroll
    for (int ni = 0; ni < 6; ni++)
        bOff[ni] = (n0 + wn * 96 + ni * 16 + fr) * DIM + fq * 8;

    f32x4 acc[2][6] = {};
    bf16x8 aP[2], bP[6], aQ[2], bQ[6];   // two named register sets (static idx)

#define LD_P(kt) do { \
    _Pragma("unroll") for (int mi = 0; mi < 2; mi++) \
        aP[mi] = *(const bf16x8*)(A + aOff[mi] + (kt) * 32); \
    _Pragma("unroll") for (int ni = 0; ni < 6; ni++) \
        bP[ni] = *(const bf16x8*)(Bw + bOff[ni] + (kt) * 32); } while (0)
#define LD_Q(kt) do { \
    _Pragma("unroll") for (int mi = 0; mi < 2; mi++) \
        aQ[mi] = *(const bf16x8*)(A + aOff[mi] + (kt) * 32); \
    _Pragma("unroll") for (int ni = 0; ni < 6; ni++) \
        bQ[ni] = *(const bf16x8*)(Bw + bOff[ni] + (kt) * 32); } while (0)
#define MM_P() do { __builtin_amdgcn_s_setprio(1); \
    _Pragma("unroll") for (int mi = 0; mi < 2; mi++) \
    _Pragma("unroll") for (int ni = 0; ni < 6; ni++) \
        acc[mi][ni] = __builtin_amdgcn_mfma_f32_16x16x32_bf16(aP[mi], bP[ni], acc[mi][ni], 0, 0, 0); \
    __builtin_amdgcn_s_setprio(0); } while (0)
#define MM_Q() do { __builtin_amdgcn_s_setprio(1); \
    _Pragma("unroll") for (int mi = 0; mi < 2; mi++) \
    _Pragma("unroll") for (int ni = 0; ni < 6; ni++) \
        acc[mi][ni] = __builtin_amdgcn_mfma_f32_16x16x32_bf16(aQ[mi], bQ[ni], acc[mi][ni], 0, 0, 0); \
    __builtin_amdgcn_s_setprio(0); } while (0)

    LD_P(0);
#pragma unroll 2
    for (int kt = 0; kt < NKT; kt += 2) {
        LD_Q(kt + 1);          // kt+1 < NKT always (NKT even)
        MM_P();
        if (kt + 2 < NKT) LD_P(kt + 2);
        MM_Q();
    }
#undef LD_P
#undef LD_Q
#undef MM_P
#undef MM_Q

    // ---------------- epilogue ----------------
    if (MODE == 0) {
        bf16* o = (bf16*)out;
#pragma unroll
        for (int mi = 0; mi < 2; mi++) {
            const int row = m0 + wm * 32 + mi * 16 + fq * 4;
#pragma unroll
            for (int ni = 0; ni < 6; ni++) {
                const int off = wn * 96 + ni * 16;
                const int col = n0 + off + fr;   // logical channel
                const int pcol = n0 + (off & ~31) + ((fr >> 2) << 3) + (fr & 3)
                               + (((off >> 4) & 1) << 2);   // k2pos
                const float bv = bias[col];
#pragma unroll
                for (int r = 0; r < 4; r++)
                    o[(size_t)(row + r) * DIM + pcol] = (bf16)(acc[mi][ni][r] + bv);
            }
        }
    } else {
        float* o = (float*)out;
#pragma unroll
        for (int mi = 0; mi < 2; mi++) {
            const int nb = m0 + wm * 32 + mi * 16 + fq * 4;
            const int bI = nb >> 10, hw = nb & 1023;
#pragma unroll
            for (int ni = 0; ni < 6; ni++) {
                const int col = n0 + wn * 96 + ni * 16 + fr;
                f32x4 v = acc[mi][ni] + bias[col];
                *(f32x4*)(o + ((size_t)bI * DIM + col) * HW + hw) = v;
            }
        }
    }
}

// ---------------- LayerNorm + exact GELU, in-place on k-permuted bf16 rows ----------------
__global__ __launch_bounds__(256) void ln_gelu_kernel(
    bf16* __restrict__ h, const float* __restrict__ g, const float* __restrict__ beta)
{
    const int wave = threadIdx.x >> 6;
    const int lane = threadIdx.x & 63;
    const int n = blockIdx.x * 4 + wave;
    bf16* row = h + (size_t)n * DIM;

    float v[12];
    float s = 0.f, ss = 0.f;
#pragma unroll
    for (int j = 0; j < 3; j++) {
        bf16x4 x = *(const bf16x4*)(row + j * 256 + lane * 4);
#pragma unroll
        for (int i = 0; i < 4; i++) {
            float f = (float)x[i];
            v[j * 4 + i] = f;
            s += f;
            ss += f * f;
        }
    }
#pragma unroll
    for (int off = 32; off > 0; off >>= 1) {
        s += __shfl_xor(s, off);
        ss += __shfl_xor(ss, off);
    }
    const float mu = s * (1.f / DIM);
    const float var = ss * (1.f / DIM) - mu * mu;
    const float rstd = rsqrtf(var + 1e-6f);

#pragma unroll
    for (int j = 0; j < 3; j++) {
        bf16x4 r;
#pragma unroll
        for (int i = 0; i < 4; i++) {
            const int c = j * 256 + lane * 4 + i;   // physical position
            const int p = (lane * 4 + i) & 31;
            const int kk = ((p >> 3) << 2) + (p & 7) + ((p & 4) ? 12 : 0);  // pos2k
            const int gi = (c & ~31) + kk;          // logical channel for gamma/beta
            float y = (v[j * 4 + i] - mu) * rstd * g[gi] + beta[gi];
            y = 0.5f * y * (1.f + erff(y * 0.70710678118f));
            r[i] = (bf16)y;
        }
        *(bf16x4*)(row + j * 256 + lane * 4) = r;
    }
}

extern "C" void kernel_launch(void* const* d_in, const int* in_sizes, int n_in,
                              void* d_out, int out_size, void* d_ws, size_t ws_size,
                              hipStream_t stream) {
    const float* x   = (const float*)d_in[0];
    const float* W1  = (const float*)d_in[1];
    const float* b1  = (const float*)d_in[2];
    const float* g1  = (const float*)d_in[3];
    const float* be1 = (const float*)d_in[4];
    const float* W2  = (const float*)d_in[5];
    const float* b2  = (const float*)d_in[6];
    const float* g2  = (const float*)d_in[7];
    const float* be2 = (const float*)d_in[8];
    const float* W3  = (const float*)d_in[9];
    const float* b3  = (const float*)d_in[10];
    float* out = (float*)d_out;

    bf16* Wb1  = (bf16*)d_ws;
    bf16* Wb2  = Wb1 + (size_t)DIM * DIM;
    bf16* Wb3  = Wb2 + (size_t)DIM * DIM;
    bf16* buf0 = Wb3 + (size_t)DIM * DIM;          // 16384*768 bf16
    bf16* buf1 = buf0 + (size_t)M_TOTAL * DIM;

    // weights -> bf16 k-permuted + x NCHW -> [n][c] bf16 k-permuted (one launch)
    prep_kernel<<<864 + 12288, 256, 0, stream>>>(
        x, buf0, (const float4*)W1, (const float4*)W2, (const float4*)W3,
        (bf16x8*)Wb1, (bf16x8*)Wb2, (bf16x8*)Wb3);

    const int ggrid = (M_TOTAL / 64) * (DIM / 192);   // 256*4 = 1024 = 4/CU
    // layer 1
    gemm_kernel<0><<<ggrid, 256, 0, stream>>>(buf0, Wb1, b1, buf1);
    ln_gelu_kernel<<<M_TOTAL / 4, 256, 0, stream>>>(buf1, g1, be1);
    // layer 2
    gemm_kernel<0><<<ggrid, 256, 0, stream>>>(buf1, Wb2, b2, buf0);
    ln_gelu_kernel<<<M_TOTAL / 4, 256, 0, stream>>>(buf0, g2, be2);
    // layer 3 -> NCHW f32 output
    gemm_kernel<1><<<ggrid, 256, 0, stream>>>(buf0, Wb3, b3, out);
}

// Round 11
// 167.549 us; speedup vs baseline: 2.5522x; 2.5522x over previous
//
#include <hip/hip_runtime.h>
#include <hip/hip_bf16.h>

typedef __bf16 bf16;
typedef __bf16 bf16x4 __attribute__((ext_vector_type(4)));
typedef __bf16 bf16x8 __attribute__((ext_vector_type(8)));
typedef float f32x4 __attribute__((ext_vector_type(4)));

#define DIM 768
#define HW 1024          // 32*32
#define BATCH 16
#define M_TOTAL (BATCH * HW)   // 16384
#define NKT 12                 // K-tiles of 64

#define AS1 __attribute__((address_space(1)))
#define AS3 __attribute__((address_space(3)))

// ======================== k-permutation convention =========================
// All bf16 [.][768] activation buffers and Wb[768][768] store the k (channel)
// dimension permuted within each 32-group: physical position p = 8g+j holds
// logical k = 4g+j (j<4) or 16+4g+(j-4) (j>=4). mfma_f32_16x16x32_bf16
// fragments are then CONTIGUOUS 16B in LDS -> single ds_read_b128 per
// fragment. k2pos(kk) = (((kk&15)>>2)<<3)+(kk&3)+((kk>>4)<<2). (validated R4-R9)

// ------------- prep: weights f32->bf16 k-permuted + x NCHW -> [n][c] bf16 -------------
// blocks 0..863: weight convert (3 x 288). blocks 864..13151: transpose.
__global__ void prep_kernel(const float* __restrict__ x, bf16* __restrict__ xb,
                            const float4* __restrict__ w1, const float4* __restrict__ w2,
                            const float4* __restrict__ w3,
                            bf16x8* __restrict__ o1, bf16x8* __restrict__ o2,
                            bf16x8* __restrict__ o3) {
    __shared__ float tile[32][33];
    if (blockIdx.x < 864) {
        const int b = blockIdx.x;
        const int which = b / 288;
        const int i = (b % 288) * 256 + threadIdx.x;
        const float4* w = which == 0 ? w1 : which == 1 ? w2 : w3;
        bf16x8* o = which == 0 ? o1 : which == 1 ? o2 : o3;
        const int row = i / 96, br = i % 96;
        const int q = br >> 2, g = br & 3;
        float4 lo = w[row * 192 + q * 8 + g];
        float4 hi = w[row * 192 + q * 8 + g + 4];
        bf16x8 r = { (bf16)lo.x, (bf16)lo.y, (bf16)lo.z, (bf16)lo.w,
                     (bf16)hi.x, (bf16)hi.y, (bf16)hi.z, (bf16)hi.w };
        o[row * 96 + br] = r;
    } else {
        const int e = blockIdx.x - 864;
        const int b = e / 768;
        const int rem = e % 768;
        const int c0 = (rem / 32) * 32;
        const int hw0 = (rem % 32) * 32;
        const int tx = threadIdx.x & 31, ty = threadIdx.x >> 5;  // 32 x 8

        const float* src = x + ((size_t)b * DIM + c0) * HW + hw0;
#pragma unroll
        for (int j = 0; j < 4; j++)
            tile[ty + 8 * j][tx] = src[(size_t)(ty + 8 * j) * HW + tx];
        __syncthreads();
        const int ptx = (((tx & 15) >> 2) << 3) + (tx & 3) + ((tx >> 4) << 2);  // k2pos
        bf16* dst = xb + ((size_t)b * HW + hw0) * DIM + c0;
#pragma unroll
        for (int j = 0; j < 4; j++)
            dst[(size_t)(ty + 8 * j) * DIM + ptx] = (bf16)tile[tx][ty + 8 * j];
    }
}

// ---------------- GEMM: 256x256 tile, BK=64, 8 waves, 8-phase schedule ----------------
// (R4 K-loop verbatim.)  MODE 0 epilogue bounces the C-tile through LDS
// (dead after the K-loop) in 4 groups of 64 rows so global stores are
// fully-coalesced bf16x8.  R11 fix vs R10: readback covers ALL 32 16B-blocks
// per row (was 16 -> half the tile stale), and explicit lgkmcnt(0) drains
// before the bounce barriers (raw s_barrier does not imply the wait).
// MODE 0: write bf16 [n][768] k-permuted (+bias). MODE 1: write f32 NCHW (+bias).
template <int MODE>
__global__ __launch_bounds__(512, 2) void gemm_kernel(
    const bf16* __restrict__ A,   // [M][768] k-permuted
    const bf16* __restrict__ Bw,  // [768][768] rows linear, cols k-permuted
    const float* __restrict__ bias,
    void* __restrict__ out)
{
    constexpr int K = DIM;
    __shared__ bf16 lds[2][2][256][64];   // [dbuf][A/B][row][k] = 128 KiB

    const int t = threadIdx.x;
    const int lane = t & 63;
    const int wave = t >> 6;
    const int wm = wave >> 2, wn = wave & 3;   // 2 x 4 waves

    const int bid = blockIdx.x;                 // 192 blocks, 192%8==0
    const int swz = (bid & 7) * 24 + (bid >> 3);
    const int m0 = (swz % 64) * 256;
    const int n0 = (swz / 64) * 256;

    const int fr = lane & 15;
    const int fq = lane >> 4;

    f32x4 acc[8][4] = {};

    const int s_r = t >> 3;     // 0..63, staging row (per j +64)
    const int s_blk = t & 7;    // staging 16B block in row

    // half-tile stage: 2 x global_load_lds, LDS dest linear,
    // source pre-swizzled with blk ^= (row&7)  (both-sides-or-neither, G21)
    auto stage_half = [&](int kt, int which, int half) {
        const int d = kt & 1;
        const bf16* src = which == 0 ? A : Bw;
        const int row0 = which == 0 ? m0 : n0;
#pragma unroll
        for (int j = 0; j < 2; j++) {
            const int r = s_r + j * 64;         // 0..127
            const int R = half * 128 + r;
            __builtin_amdgcn_global_load_lds(
                (const AS1 void*)(src + (size_t)(row0 + R) * K + kt * 64 + ((s_blk ^ (r & 7)) << 3)),
                (AS3 void*)&lds[d][which][R][s_blk * 8], 16, 0, 0);
        }
    };

    bf16x8 a[8], b0[4], b1[4];

    auto ldA = [&](int kt, int mh) {   // 8 x ds_read_b128
        const int d = kt & 1;
#pragma unroll
        for (int mi = 0; mi < 4; mi++) {
            const int R = wm * 128 + (mh * 4 + mi) * 16 + fr;
            const bf16* rp = &lds[d][0][R][0];
            const int s = R & 7;
#pragma unroll
            for (int ks = 0; ks < 2; ks++)
                a[mi * 2 + ks] = *(const bf16x8*)(rp + (((ks * 4 + fq) ^ s) << 3));
        }
    };
    auto ldB = [&](bf16x8* bb, int kt, int nh) {   // 4 x ds_read_b128
        const int d = kt & 1;
#pragma unroll
        for (int ni = 0; ni < 2; ni++) {
            const int R = wn * 64 + (nh * 2 + ni) * 16 + fr;
            const bf16* rp = &lds[d][1][R][0];
            const int s = R & 7;
#pragma unroll
            for (int ks = 0; ks < 2; ks++)
                bb[ni * 2 + ks] = *(const bf16x8*)(rp + (((ks * 4 + fq) ^ s) << 3));
        }
    };
    auto MM = [&](bf16x8* bb, int mh, int nh) {    // 16 MFMA, setprio-wrapped (T5)
        __builtin_amdgcn_s_setprio(1);
#pragma unroll
        for (int mi = 0; mi < 4; mi++)
#pragma unroll
            for (int ni = 0; ni < 2; ni++)
#pragma unroll
                for (int ks = 0; ks < 2; ks++)
                    acc[mh * 4 + mi][nh * 2 + ni] = __builtin_amdgcn_mfma_f32_16x16x32_bf16(
                        a[mi * 2 + ks], bb[ni * 2 + ks], acc[mh * 4 + mi][nh * 2 + ni], 0, 0, 0);
        __builtin_amdgcn_s_setprio(0);
    };

    // prologue: kt0 fully + kt1's A-h0; vmcnt(2) -> kt0 resident, kt1-Ah0 in flight
    stage_half(0, 0, 0); stage_half(0, 0, 1); stage_half(0, 1, 0); stage_half(0, 1, 1);
    stage_half(1, 0, 0);
    asm volatile("s_waitcnt vmcnt(2)" ::: "memory");
    __builtin_amdgcn_s_barrier();

    for (int kt = 0; kt < NKT; ++kt) {
        // P0: quadrant (mh0, nh0); stage (kt+1, A-h1) into other dbuf
        ldA(kt, 0);
        ldB(b0, kt, 0);
        if (kt + 1 < NKT) stage_half(kt + 1, 0, 1);
        __builtin_amdgcn_s_barrier();
        asm volatile("s_waitcnt lgkmcnt(0)" ::: "memory");
        MM(b0, 0, 0);
        __builtin_amdgcn_s_barrier();
        // P1: (mh0, nh1); stage (kt+1, B-h0)
        ldB(b1, kt, 1);
        if (kt + 1 < NKT) stage_half(kt + 1, 1, 0);
        __builtin_amdgcn_s_barrier();
        asm volatile("s_waitcnt lgkmcnt(0)" ::: "memory");
        MM(b1, 0, 1);
        __builtin_amdgcn_s_barrier();
        // P2: (mh1, nh1); stage (kt+1, B-h1); last ds_reads of this dbuf
        ldA(kt, 1);
        if (kt + 1 < NKT) stage_half(kt + 1, 1, 1);
        __builtin_amdgcn_s_barrier();
        asm volatile("s_waitcnt lgkmcnt(0)" ::: "memory");
        MM(b1, 1, 1);
        __builtin_amdgcn_s_barrier();
        // P3: (mh1, nh0) from registers; stage (kt+2, A-h0) into the dbuf just
        // freed. Counted vmcnt: keep only newest half-tile in flight.
        if (kt + 2 < NKT) stage_half(kt + 2, 0, 0);
        MM(b0, 1, 0);
        if (kt < NKT - 2) { asm volatile("s_waitcnt vmcnt(2)" ::: "memory"); }
        else if (kt == NKT - 2) { asm volatile("s_waitcnt vmcnt(0)" ::: "memory"); }
        __builtin_amdgcn_s_barrier();
    }

    // ---------------- epilogue ----------------
    const int fq4 = fq * 4;
    if (MODE == 0) {
        // LDS bounce: 4 groups of (mi pair) = 64 chunk-rows x 256 phys cols.
        // chunk row cr = wm*32 + mm*16 + fq*4 + r ; stride 280 spreads banks.
        bf16* eb = (bf16*)lds;            // K-loop LDS is dead after final barrier
        bf16* o = (bf16*)out;
#pragma unroll
        for (int g = 0; g < 4; ++g) {
#pragma unroll
            for (int mm = 0; mm < 2; ++mm) {
                const int mi = 2 * g + mm;
                const int cr0 = wm * 32 + mm * 16 + fq4;
#pragma unroll
                for (int ni = 0; ni < 4; ++ni) {
                    const int pcol = wn * 64 + ((ni >> 1) << 5) + ((fr >> 2) << 3)
                                   + (fr & 3) + ((ni & 1) << 2);   // k2pos position
                    const float bv = bias[n0 + wn * 64 + ni * 16 + fr];
#pragma unroll
                    for (int r = 0; r < 4; ++r)
                        eb[(cr0 + r) * 280 + pcol] = (bf16)(acc[mi][ni][r] + bv);
                }
            }
            asm volatile("s_waitcnt lgkmcnt(0)" ::: "memory");  // ds_writes visible
            __builtin_amdgcn_s_barrier();
            // read back coalesced: 2048 x 16B units, 4 per thread (ALL 32 blks/row)
#pragma unroll
            for (int u = 0; u < 4; ++u) {
                const int unit = t * 4 + u;         // 0..2047
                const int crr = unit >> 5;          // 0..63
                const int blk = unit & 31;          // 0..31
                bf16x8 v = *(const bf16x8*)&eb[crr * 280 + blk * 8];
                const int grow = m0 + (crr >> 5) * 128 + (2 * g + ((crr >> 4) & 1)) * 16 + (crr & 15);
                *(bf16x8*)&o[(size_t)grow * DIM + n0 + blk * 8] = v;
            }
            if (g < 3) {
                asm volatile("s_waitcnt lgkmcnt(0)" ::: "memory");  // reads done before overwrite
                __builtin_amdgcn_s_barrier();
            }
        }
    } else {
        float* o = (float*)out;
#pragma unroll
        for (int mi = 0; mi < 8; mi++) {
            const int nb = m0 + wm * 128 + mi * 16 + fq4;
            const int bI = nb >> 10, hw = nb & 1023;
#pragma unroll
            for (int ni = 0; ni < 4; ni++) {
                const int col = n0 + wn * 64 + ni * 16 + fr;
                f32x4 v = acc[mi][ni] + bias[col];
                *(f32x4*)(o + ((size_t)bI * DIM + col) * HW + hw) = v;
            }
        }
    }
}

// ---------------- LayerNorm + exact GELU, in-place on k-permuted bf16 rows ----------------
__global__ __launch_bounds__(256) void ln_gelu_kernel(
    bf16* __restrict__ h, const float* __restrict__ g, const float* __restrict__ beta)
{
    const int wave = threadIdx.x >> 6;
    const int lane = threadIdx.x & 63;
    const int n = blockIdx.x * 4 + wave;
    bf16* row = h + (size_t)n * DIM;

    float v[12];
    float s = 0.f, ss = 0.f;
#pragma unroll
    for (int j = 0; j < 3; j++) {
        bf16x4 x = *(const bf16x4*)(row + j * 256 + lane * 4);
#pragma unroll
        for (int i = 0; i < 4; i++) {
            float f = (float)x[i];
            v[j * 4 + i] = f;
            s += f;
            ss += f * f;
        }
    }
#pragma unroll
    for (int off = 32; off > 0; off >>= 1) {
        s += __shfl_xor(s, off);
        ss += __shfl_xor(ss, off);
    }
    const float mu = s * (1.f / DIM);
    const float var = ss * (1.f / DIM) - mu * mu;
    const float rstd = rsqrtf(var + 1e-6f);

#pragma unroll
    for (int j = 0; j < 3; j++) {
        bf16x4 r;
#pragma unroll
        for (int i = 0; i < 4; i++) {
            const int c = j * 256 + lane * 4 + i;   // physical position
            const int p = (lane * 4 + i) & 31;
            const int kk = ((p >> 3) << 2) + (p & 7) + ((p & 4) ? 12 : 0);  // pos2k
            const int gi = (c & ~31) + kk;          // logical channel for gamma/beta
            float y = (v[j * 4 + i] - mu) * rstd * g[gi] + beta[gi];
            y = 0.5f * y * (1.f + erff(y * 0.70710678118f));
            r[i] = (bf16)y;
        }
        *(bf16x4*)(row + j * 256 + lane * 4) = r;
    }
}

extern "C" void kernel_launch(void* const* d_in, const int* in_sizes, int n_in,
                              void* d_out, int out_size, void* d_ws, size_t ws_size,
                              hipStream_t stream) {
    const float* x   = (const float*)d_in[0];
    const float* W1  = (const float*)d_in[1];
    const float* b1  = (const float*)d_in[2];
    const float* g1  = (const float*)d_in[3];
    const float* be1 = (const float*)d_in[4];
    const float* W2  = (const float*)d_in[5];
    const float* b2  = (const float*)d_in[6];
    const float* g2  = (const float*)d_in[7];
    const float* be2 = (const float*)d_in[8];
    const float* W3  = (const float*)d_in[9];
    const float* b3  = (const float*)d_in[10];
    float* out = (float*)d_out;

    bf16* Wb1  = (bf16*)d_ws;
    bf16* Wb2  = Wb1 + (size_t)DIM * DIM;
    bf16* Wb3  = Wb2 + (size_t)DIM * DIM;
    bf16* buf0 = Wb3 + (size_t)DIM * DIM;          // 16384*768 bf16
    bf16* buf1 = buf0 + (size_t)M_TOTAL * DIM;

    // weights -> bf16 k-permuted + x NCHW -> [n][c] bf16 k-permuted (one launch)
    prep_kernel<<<864 + 12288, 256, 0, stream>>>(
        x, buf0, (const float4*)W1, (const float4*)W2, (const float4*)W3,
        (bf16x8*)Wb1, (bf16x8*)Wb2, (bf16x8*)Wb3);

    const int ggrid = (M_TOTAL / 256) * (DIM / 256);   // 64*3 = 192
    // layer 1
    gemm_kernel<0><<<ggrid, 512, 0, stream>>>(buf0, Wb1, b1, buf1);
    ln_gelu_kernel<<<M_TOTAL / 4, 256, 0, stream>>>(buf1, g1, be1);
    // layer 2
    gemm_kernel<0><<<ggrid, 512, 0, stream>>>(buf1, Wb2, b2, buf0);
    ln_gelu_kernel<<<M_TOTAL / 4, 256, 0, stream>>>(buf0, g2, be2);
    // layer 3 -> NCHW f32 output
    gemm_kernel<1><<<ggrid, 512, 0, stream>>>(buf0, Wb3, b3, out);
}

// Round 12
// 150.687 us; speedup vs baseline: 2.8378x; 1.1119x over previous
//
#include <hip/hip_runtime.h>
#include <hip/hip_bf16.h>

typedef __bf16 bf16;
typedef __bf16 bf16x4 __attribute__((ext_vector_type(4)));
typedef __bf16 bf16x8 __attribute__((ext_vector_type(8)));
typedef float f32x4 __attribute__((ext_vector_type(4)));

#define DIM 768
#define HW 1024          // 32*32
#define BATCH 16
#define M_TOTAL (BATCH * HW)   // 16384
#define NKT 12                 // K-tiles of 64

#define AS1 __attribute__((address_space(1)))
#define AS3 __attribute__((address_space(3)))

// ======================== k-permutation convention =========================
// All bf16 [.][768] activation buffers and Wb[768][768] store the k (channel)
// dimension permuted within each 32-group: physical position p = 8g+j holds
// logical k = 4g+j (j<4) or 16+4g+(j-4) (j>=4). mfma_f32_16x16x32_bf16
// fragments are then CONTIGUOUS 16B in LDS -> single ds_read_b128 per
// fragment. k2pos(kk) = (((kk&15)>>2)<<3)+(kk&3)+((kk>>4)<<2). (validated R4-R11)

// ------------- prep: weights f32->bf16 k-permuted + x NCHW -> [n][c] bf16 -------------
// blocks 0..863: weight convert (3 x 288). blocks 864..13151: transpose.
__global__ void prep_kernel(const float* __restrict__ x, bf16* __restrict__ xb,
                            const float4* __restrict__ w1, const float4* __restrict__ w2,
                            const float4* __restrict__ w3,
                            bf16x8* __restrict__ o1, bf16x8* __restrict__ o2,
                            bf16x8* __restrict__ o3) {
    __shared__ float tile[32][33];
    if (blockIdx.x < 864) {
        const int b = blockIdx.x;
        const int which = b / 288;
        const int i = (b % 288) * 256 + threadIdx.x;
        const float4* w = which == 0 ? w1 : which == 1 ? w2 : w3;
        bf16x8* o = which == 0 ? o1 : which == 1 ? o2 : o3;
        const int row = i / 96, br = i % 96;
        const int q = br >> 2, g = br & 3;
        float4 lo = w[row * 192 + q * 8 + g];
        float4 hi = w[row * 192 + q * 8 + g + 4];
        bf16x8 r = { (bf16)lo.x, (bf16)lo.y, (bf16)lo.z, (bf16)lo.w,
                     (bf16)hi.x, (bf16)hi.y, (bf16)hi.z, (bf16)hi.w };
        o[row * 96 + br] = r;
    } else {
        const int e = blockIdx.x - 864;
        const int b = e / 768;
        const int rem = e % 768;
        const int c0 = (rem / 32) * 32;
        const int hw0 = (rem % 32) * 32;
        const int tx = threadIdx.x & 31, ty = threadIdx.x >> 5;  // 32 x 8

        const float* src = x + ((size_t)b * DIM + c0) * HW + hw0;
#pragma unroll
        for (int j = 0; j < 4; j++)
            tile[ty + 8 * j][tx] = src[(size_t)(ty + 8 * j) * HW + tx];
        __syncthreads();
        const int ptx = (((tx & 15) >> 2) << 3) + (tx & 3) + ((tx >> 4) << 2);  // k2pos
        bf16* dst = xb + ((size_t)b * HW + hw0) * DIM + c0;
#pragma unroll
        for (int j = 0; j < 4; j++)
            dst[(size_t)(ty + 8 * j) * DIM + ptx] = (bf16)tile[tx][ty + 8 * j];
    }
}

// ---------------- GEMM: 256x256 tile, BK=64, 8 waves ----------------
// R4's 8-phase K-loop with the 6 PACING barriers per K-tile removed; only the
// 2 hazard-bearing barriers remain: (i) before P3's stage of kt+2-A-h0 into
// the CURRENT dbuf (all waves' reads of it are lgkm-complete at arrival),
// (ii) kt-end after counted vmcnt(2) (kt+1 fully resident across waves).
// Per-wave lgkmcnt(0) before each MFMA cluster covers read-use ordering.
// MODE 0: write bf16 [n][768] k-permuted (+bias). MODE 1: write f32 NCHW (+bias).
template <int MODE>
__global__ __launch_bounds__(512, 2) void gemm_kernel(
    const bf16* __restrict__ A,   // [M][768] k-permuted
    const bf16* __restrict__ Bw,  // [768][768] rows linear, cols k-permuted
    const float* __restrict__ bias,
    void* __restrict__ out)
{
    constexpr int K = DIM;
    __shared__ bf16 lds[2][2][256][64];   // [dbuf][A/B][row][k] = 128 KiB

    const int t = threadIdx.x;
    const int lane = t & 63;
    const int wave = t >> 6;
    const int wm = wave >> 2, wn = wave & 3;   // 2 x 4 waves

    const int bid = blockIdx.x;                 // 192 blocks, 192%8==0
    const int swz = (bid & 7) * 24 + (bid >> 3);
    const int m0 = (swz % 64) * 256;
    const int n0 = (swz / 64) * 256;

    const int fr = lane & 15;
    const int fq = lane >> 4;

    f32x4 acc[8][4] = {};

    const int s_r = t >> 3;     // 0..63, staging row (per j +64)
    const int s_blk = t & 7;    // staging 16B block in row

    // half-tile stage: 2 x global_load_lds, LDS dest linear,
    // source pre-swizzled with blk ^= (row&7)  (both-sides-or-neither, G21)
    auto stage_half = [&](int kt, int which, int half) {
        const int d = kt & 1;
        const bf16* src = which == 0 ? A : Bw;
        const int row0 = which == 0 ? m0 : n0;
#pragma unroll
        for (int j = 0; j < 2; j++) {
            const int r = s_r + j * 64;         // 0..127
            const int R = half * 128 + r;
            __builtin_amdgcn_global_load_lds(
                (const AS1 void*)(src + (size_t)(row0 + R) * K + kt * 64 + ((s_blk ^ (r & 7)) << 3)),
                (AS3 void*)&lds[d][which][R][s_blk * 8], 16, 0, 0);
        }
    };

    bf16x8 a[8], b0[4], b1[4];

    auto ldA = [&](int kt, int mh) {   // 8 x ds_read_b128
        const int d = kt & 1;
#pragma unroll
        for (int mi = 0; mi < 4; mi++) {
            const int R = wm * 128 + (mh * 4 + mi) * 16 + fr;
            const bf16* rp = &lds[d][0][R][0];
            const int s = R & 7;
#pragma unroll
            for (int ks = 0; ks < 2; ks++)
                a[mi * 2 + ks] = *(const bf16x8*)(rp + (((ks * 4 + fq) ^ s) << 3));
        }
    };
    auto ldB = [&](bf16x8* bb, int kt, int nh) {   // 4 x ds_read_b128
        const int d = kt & 1;
#pragma unroll
        for (int ni = 0; ni < 2; ni++) {
            const int R = wn * 64 + (nh * 2 + ni) * 16 + fr;
            const bf16* rp = &lds[d][1][R][0];
            const int s = R & 7;
#pragma unroll
            for (int ks = 0; ks < 2; ks++)
                bb[ni * 2 + ks] = *(const bf16x8*)(rp + (((ks * 4 + fq) ^ s) << 3));
        }
    };
    auto MM = [&](bf16x8* bb, int mh, int nh) {    // 16 MFMA, setprio-wrapped (T5)
        __builtin_amdgcn_s_setprio(1);
#pragma unroll
        for (int mi = 0; mi < 4; mi++)
#pragma unroll
            for (int ni = 0; ni < 2; ni++)
#pragma unroll
                for (int ks = 0; ks < 2; ks++)
                    acc[mh * 4 + mi][nh * 2 + ni] = __builtin_amdgcn_mfma_f32_16x16x32_bf16(
                        a[mi * 2 + ks], bb[ni * 2 + ks], acc[mh * 4 + mi][nh * 2 + ni], 0, 0, 0);
        __builtin_amdgcn_s_setprio(0);
    };

    // prologue: kt0 fully + kt1's A-h0; vmcnt(2) -> kt0 resident, kt1-Ah0 in flight
    stage_half(0, 0, 0); stage_half(0, 0, 1); stage_half(0, 1, 0); stage_half(0, 1, 1);
    stage_half(1, 0, 0);
    asm volatile("s_waitcnt vmcnt(2)" ::: "memory");
    __builtin_amdgcn_s_barrier();

    for (int kt = 0; kt < NKT; ++kt) {
        // free-running phases (per-wave lgkm waits only)
        ldA(kt, 0);
        ldB(b0, kt, 0);
        if (kt + 1 < NKT) stage_half(kt + 1, 0, 1);
        asm volatile("s_waitcnt lgkmcnt(0)" ::: "memory");
        MM(b0, 0, 0);

        ldB(b1, kt, 1);
        if (kt + 1 < NKT) stage_half(kt + 1, 1, 0);
        asm volatile("s_waitcnt lgkmcnt(0)" ::: "memory");
        MM(b1, 0, 1);

        ldA(kt, 1);
        if (kt + 1 < NKT) stage_half(kt + 1, 1, 1);
        asm volatile("s_waitcnt lgkmcnt(0)" ::: "memory");
        MM(b1, 1, 1);

        // hazard barrier (i): every wave's reads of dbuf d are complete
        // (each wave passed its own lgkmcnt(0) before arriving).
        __builtin_amdgcn_s_barrier();
        if (kt + 2 < NKT) stage_half(kt + 2, 0, 0);   // writes into dbuf d
        MM(b0, 1, 0);

        // hazard barrier (ii): kt+1 resident for all waves before next iter.
        if (kt < NKT - 2) {
            asm volatile("s_waitcnt vmcnt(2)" ::: "memory");
            __builtin_amdgcn_s_barrier();
        } else if (kt == NKT - 2) {
            asm volatile("s_waitcnt vmcnt(0)" ::: "memory");
            __builtin_amdgcn_s_barrier();
        }
        __builtin_amdgcn_sched_barrier(0);   // no next-iter ds_read hoists above barrier
    }

    // ---------------- epilogue (R4 scattered stores — bounce was a regression) ----------------
    const int fq4 = fq * 4;
    if (MODE == 0) {
        bf16* o = (bf16*)out;
#pragma unroll
        for (int mi = 0; mi < 8; mi++) {
            const int row = m0 + wm * 128 + mi * 16 + fq4;
#pragma unroll
            for (int ni = 0; ni < 4; ni++) {
                const int col = n0 + wn * 64 + ni * 16 + fr;   // logical channel
                const int pcol = n0 + wn * 64 + ((ni >> 1) << 5)
                               + ((fr >> 2) << 3) + (fr & 3) + ((ni & 1) << 2); // k2pos
                const float bv = bias[col];
#pragma unroll
                for (int r = 0; r < 4; r++)
                    o[(size_t)(row + r) * DIM + pcol] = (bf16)(acc[mi][ni][r] + bv);
            }
        }
    } else {
        float* o = (float*)out;
#pragma unroll
        for (int mi = 0; mi < 8; mi++) {
            const int nb = m0 + wm * 128 + mi * 16 + fq4;
            const int bI = nb >> 10, hw = nb & 1023;
#pragma unroll
            for (int ni = 0; ni < 4; ni++) {
                const int col = n0 + wn * 64 + ni * 16 + fr;
                f32x4 v = acc[mi][ni] + bias[col];
                *(f32x4*)(o + ((size_t)bI * DIM + col) * HW + hw) = v;
            }
        }
    }
}

// ---------------- LayerNorm + exact GELU, in-place on k-permuted bf16 rows ----------------
__global__ __launch_bounds__(256) void ln_gelu_kernel(
    bf16* __restrict__ h, const float* __restrict__ g, const float* __restrict__ beta)
{
    const int wave = threadIdx.x >> 6;
    const int lane = threadIdx.x & 63;
    const int n = blockIdx.x * 4 + wave;
    bf16* row = h + (size_t)n * DIM;

    float v[12];
    float s = 0.f, ss = 0.f;
#pragma unroll
    for (int j = 0; j < 3; j++) {
        bf16x4 x = *(const bf16x4*)(row + j * 256 + lane * 4);
#pragma unroll
        for (int i = 0; i < 4; i++) {
            float f = (float)x[i];
            v[j * 4 + i] = f;
            s += f;
            ss += f * f;
        }
    }
#pragma unroll
    for (int off = 32; off > 0; off >>= 1) {
        s += __shfl_xor(s, off);
        ss += __shfl_xor(ss, off);
    }
    const float mu = s * (1.f / DIM);
    const float var = ss * (1.f / DIM) - mu * mu;
    const float rstd = rsqrtf(var + 1e-6f);

#pragma unroll
    for (int j = 0; j < 3; j++) {
        bf16x4 r;
#pragma unroll
        for (int i = 0; i < 4; i++) {
            const int c = j * 256 + lane * 4 + i;   // physical position
            const int p = (lane * 4 + i) & 31;
            const int kk = ((p >> 3) << 2) + (p & 7) + ((p & 4) ? 12 : 0);  // pos2k
            const int gi = (c & ~31) + kk;          // logical channel for gamma/beta
            float y = (v[j * 4 + i] - mu) * rstd * g[gi] + beta[gi];
            y = 0.5f * y * (1.f + erff(y * 0.70710678118f));
            r[i] = (bf16)y;
        }
        *(bf16x4*)(row + j * 256 + lane * 4) = r;
    }
}

extern "C" void kernel_launch(void* const* d_in, const int* in_sizes, int n_in,
                              void* d_out, int out_size, void* d_ws, size_t ws_size,
                              hipStream_t stream) {
    const float* x   = (const float*)d_in[0];
    const float* W1  = (const float*)d_in[1];
    const float* b1  = (const float*)d_in[2];
    const float* g1  = (const float*)d_in[3];
    const float* be1 = (const float*)d_in[4];
    const float* W2  = (const float*)d_in[5];
    const float* b2  = (const float*)d_in[6];
    const float* g2  = (const float*)d_in[7];
    const float* be2 = (const float*)d_in[8];
    const float* W3  = (const float*)d_in[9];
    const float* b3  = (const float*)d_in[10];
    float* out = (float*)d_out;

    bf16* Wb1  = (bf16*)d_ws;
    bf16* Wb2  = Wb1 + (size_t)DIM * DIM;
    bf16* Wb3  = Wb2 + (size_t)DIM * DIM;
    bf16* buf0 = Wb3 + (size_t)DIM * DIM;          // 16384*768 bf16
    bf16* buf1 = buf0 + (size_t)M_TOTAL * DIM;

    // weights -> bf16 k-permuted + x NCHW -> [n][c] bf16 k-permuted (one launch)
    prep_kernel<<<864 + 12288, 256, 0, stream>>>(
        x, buf0, (const float4*)W1, (const float4*)W2, (const float4*)W3,
        (bf16x8*)Wb1, (bf16x8*)Wb2, (bf16x8*)Wb3);

    const int ggrid = (M_TOTAL / 256) * (DIM / 256);   // 64*3 = 192
    // layer 1
    gemm_kernel<0><<<ggrid, 512, 0, stream>>>(buf0, Wb1, b1, buf1);
    ln_gelu_kernel<<<M_TOTAL / 4, 256, 0, stream>>>(buf1, g1, be1);
    // layer 2
    gemm_kernel<0><<<ggrid, 512, 0, stream>>>(buf1, Wb2, b2, buf0);
    ln_gelu_kernel<<<M_TOTAL / 4, 256, 0, stream>>>(buf0, g2, be2);
    // layer 3 -> NCHW f32 output
    gemm_kernel<1><<<ggrid, 512, 0, stream>>>(buf0, Wb3, b3, out);
}

// Round 13
// 142.106 us; speedup vs baseline: 3.0092x; 1.0604x over previous
//
#include <hip/hip_runtime.h>
#include <hip/hip_bf16.h>

typedef __bf16 bf16;
typedef __bf16 bf16x4 __attribute__((ext_vector_type(4)));
typedef __bf16 bf16x8 __attribute__((ext_vector_type(8)));
typedef float f32x4 __attribute__((ext_vector_type(4)));

#define DIM 768
#define HW 1024          // 32*32
#define BATCH 16
#define M_TOTAL (BATCH * HW)   // 16384
#define NKT 12                 // K-tiles of 64

#define AS1 __attribute__((address_space(1)))
#define AS3 __attribute__((address_space(3)))

// ======================== k-permutation convention =========================
// All bf16 [.][768] activation buffers and Wb[768][768] store the k (channel)
// dimension permuted within each 32-group: physical position p = 8g+j holds
// logical k = 4g+j (j<4) or 16+4g+(j-4) (j>=4). mfma_f32_16x16x32_bf16
// fragments are then CONTIGUOUS 16B in LDS -> single ds_read_b128 per
// fragment. k2pos(kk) = (((kk&15)>>2)<<3)+(kk&3)+((kk>>4)<<2). (validated R4-R12)

// ------------- prep: weights f32->bf16 k-permuted + x NCHW -> [n][c] bf16 -------------
__global__ void prep_kernel(const float* __restrict__ x, bf16* __restrict__ xb,
                            const float4* __restrict__ w1, const float4* __restrict__ w2,
                            const float4* __restrict__ w3,
                            bf16x8* __restrict__ o1, bf16x8* __restrict__ o2,
                            bf16x8* __restrict__ o3) {
    __shared__ float tile[32][33];
    if (blockIdx.x < 864) {
        const int b = blockIdx.x;
        const int which = b / 288;
        const int i = (b % 288) * 256 + threadIdx.x;
        const float4* w = which == 0 ? w1 : which == 1 ? w2 : w3;
        bf16x8* o = which == 0 ? o1 : which == 1 ? o2 : o3;
        const int row = i / 96, br = i % 96;
        const int q = br >> 2, g = br & 3;
        float4 lo = w[row * 192 + q * 8 + g];
        float4 hi = w[row * 192 + q * 8 + g + 4];
        bf16x8 r = { (bf16)lo.x, (bf16)lo.y, (bf16)lo.z, (bf16)lo.w,
                     (bf16)hi.x, (bf16)hi.y, (bf16)hi.z, (bf16)hi.w };
        o[row * 96 + br] = r;
    } else {
        const int e = blockIdx.x - 864;
        const int b = e / 768;
        const int rem = e % 768;
        const int c0 = (rem / 32) * 32;
        const int hw0 = (rem % 32) * 32;
        const int tx = threadIdx.x & 31, ty = threadIdx.x >> 5;  // 32 x 8

        const float* src = x + ((size_t)b * DIM + c0) * HW + hw0;
#pragma unroll
        for (int j = 0; j < 4; j++)
            tile[ty + 8 * j][tx] = src[(size_t)(ty + 8 * j) * HW + tx];
        __syncthreads();
        const int ptx = (((tx & 15) >> 2) << 3) + (tx & 3) + ((tx >> 4) << 2);  // k2pos
        bf16* dst = xb + ((size_t)b * HW + hw0) * DIM + c0;
#pragma unroll
        for (int j = 0; j < 4; j++)
            dst[(size_t)(ty + 8 * j) * DIM + ptx] = (bf16)tile[tx][ty + 8 * j];
    }
}

// ---------------- GEMM: 256x192 tile, BK=64, 8 waves (2x4), free-running ----------------
// grid = 64 m-tiles x 4 n-tiles = 256 blocks = EVERY CU busy (R12 had 192
// blocks / 1 per CU -> 64 CUs idle). LDS 112 KB: A[2][256][64] + B[2][192][64].
// R12's free-running loop: per-wave lgkmcnt(0) before MFMA clusters; only 2
// hazard barriers per K-tile: (i) before staging kt+2 A0,A1 into current dbuf
// (all waves' reads done), (ii) kt-end after counted vmcnt(2) (kt+1 resident).
// Staging = 7 chunks of 64 rows (A0..A3,B0..B2), 1 gload_lds/thread each.
// MODE 0: write bf16 [n][768] k-permuted (+bias). MODE 1: write f32 NCHW (+bias).
template <int MODE>
__global__ __launch_bounds__(512, 2) void gemm_kernel(
    const bf16* __restrict__ A,   // [M][768] k-permuted
    const bf16* __restrict__ Bw,  // [768][768] rows linear, cols k-permuted
    const float* __restrict__ bias,
    void* __restrict__ out)
{
    constexpr int K = DIM;
    __shared__ bf16 ldsA[2][256][64];   // 64 KiB
    __shared__ bf16 ldsB[2][192][64];   // 48 KiB

    const int t = threadIdx.x;
    const int lane = t & 63;
    const int wave = t >> 6;
    const int wm = wave >> 2, wn = wave & 3;   // 2 x 4 -> wave tile 128 x 48

    const int bid = blockIdx.x;                 // 256 blocks, 256%8==0
    const int virt = (bid & 7) * 32 + (bid >> 3);
    const int m0 = (virt >> 2) * 256;           // 64 m-tiles
    const int n0 = (virt & 3) * 192;            // 4 n-tiles (n fastest: share A)

    const int fr = lane & 15;
    const int fq = lane >> 4;

    f32x4 acc[8][3] = {};

    const int s_r = t >> 3;     // 0..63, staging row within chunk
    const int s_blk = t & 7;    // staging 16B block in row

    // chunk c: 0..3 = A rows c*64.., 4..6 = B rows (c-4)*64..
    auto stage_chunk = [&](int kt, int c) {
        const int d = kt & 1;
        if (c < 4) {
            const int r = c * 64 + s_r;
            __builtin_amdgcn_global_load_lds(
                (const AS1 void*)(A + (size_t)(m0 + r) * K + kt * 64 + ((s_blk ^ (r & 7)) << 3)),
                (AS3 void*)&ldsA[d][r][s_blk * 8], 16, 0, 0);
        } else {
            const int r = (c - 4) * 64 + s_r;
            __builtin_amdgcn_global_load_lds(
                (const AS1 void*)(Bw + (size_t)(n0 + r) * K + kt * 64 + ((s_blk ^ (r & 7)) << 3)),
                (AS3 void*)&ldsB[d][r][s_blk * 8], 16, 0, 0);
        }
    };

    bf16x8 a[8], b[6];

    auto ldA = [&](int kt, int mh) {   // 8 x ds_read_b128
        const int d = kt & 1;
#pragma unroll
        for (int mi = 0; mi < 4; mi++) {
            const int R = wm * 128 + (mh * 4 + mi) * 16 + fr;
            const bf16* rp = &ldsA[d][R][0];
            const int s = R & 7;
#pragma unroll
            for (int ks = 0; ks < 2; ks++)
                a[mi * 2 + ks] = *(const bf16x8*)(rp + (((ks * 4 + fq) ^ s) << 3));
        }
    };
    auto ldB = [&](int kt) {           // 6 x ds_read_b128 (all 3 n-frags)
        const int d = kt & 1;
#pragma unroll
        for (int j = 0; j < 3; j++) {
            const int R = wn * 48 + j * 16 + fr;
            const bf16* rp = &ldsB[d][R][0];
            const int s = R & 7;
#pragma unroll
            for (int ks = 0; ks < 2; ks++)
                b[j * 2 + ks] = *(const bf16x8*)(rp + (((ks * 4 + fq) ^ s) << 3));
        }
    };
    // MFMA cluster over mh half-rows and n-frags [j0, j1)
    auto MM = [&](int mh, int j0, int j1) {
        __builtin_amdgcn_s_setprio(1);
#pragma unroll
        for (int mi = 0; mi < 4; mi++)
#pragma unroll
            for (int j = 0; j < 3; j++)
                if (j >= j0 && j < j1)
#pragma unroll
                    for (int ks = 0; ks < 2; ks++)
                        acc[mh * 4 + mi][j] = __builtin_amdgcn_mfma_f32_16x16x32_bf16(
                            a[mi * 2 + ks], b[j * 2 + ks], acc[mh * 4 + mi][j], 0, 0, 0);
        __builtin_amdgcn_s_setprio(0);
    };

    // prologue: kt0 all 7 chunks + kt1 A0,A1 -> vmcnt(2): kt0 resident
#pragma unroll
    for (int c = 0; c < 7; c++) stage_chunk(0, c);
    stage_chunk(1, 0); stage_chunk(1, 1);
    asm volatile("s_waitcnt vmcnt(2)" ::: "memory");
    __builtin_amdgcn_s_barrier();

    for (int kt = 0; kt < NKT; ++kt) {
        // P1: mh0 x all n; stage kt+1 A2,A3,B0
        ldA(kt, 0);
        ldB(kt);
        if (kt + 1 < NKT) { stage_chunk(kt + 1, 2); stage_chunk(kt + 1, 3); stage_chunk(kt + 1, 4); }
        asm volatile("s_waitcnt lgkmcnt(0)" ::: "memory");
        MM(0, 0, 3);                    // 24 MFMA

        // P2: mh1 x n{0,1}; stage kt+1 B1,B2
        ldA(kt, 1);
        if (kt + 1 < NKT) { stage_chunk(kt + 1, 5); stage_chunk(kt + 1, 6); }
        asm volatile("s_waitcnt lgkmcnt(0)" ::: "memory");
        MM(1, 0, 2);                    // 16 MFMA

        // hazard barrier (i): all waves' reads of dbuf d complete
        __builtin_amdgcn_s_barrier();
        if (kt + 2 < NKT) { stage_chunk(kt + 2, 0); stage_chunk(kt + 2, 1); }  // into dbuf d
        MM(1, 2, 3);                    // 8 MFMA (covers stage issue)

        // hazard barrier (ii): kt+1 resident for all waves before next iter
        if (kt < NKT - 2) {
            asm volatile("s_waitcnt vmcnt(2)" ::: "memory");
            __builtin_amdgcn_s_barrier();
        } else if (kt == NKT - 2) {
            asm volatile("s_waitcnt vmcnt(0)" ::: "memory");
            __builtin_amdgcn_s_barrier();
        }
        __builtin_amdgcn_sched_barrier(0);   // no next-iter ds_read hoists above barrier
    }

    // ---------------- epilogue ----------------
    const int fq4 = fq * 4;
    if (MODE == 0) {
        bf16* o = (bf16*)out;
#pragma unroll
        for (int mi = 0; mi < 8; mi++) {
            const int row = m0 + wm * 128 + mi * 16 + fq4;
#pragma unroll
            for (int j = 0; j < 3; j++) {
                const int gcol = n0 + wn * 48 + j * 16 + fr;   // logical channel
                const int kk = gcol & 31;
                const int pcol = (gcol & ~31) + (((kk & 15) >> 2) << 3) + (kk & 3)
                               + ((kk >> 4) << 2);             // k2pos
                const float bv = bias[gcol];
#pragma unroll
                for (int r = 0; r < 4; r++)
                    o[(size_t)(row + r) * DIM + pcol] = (bf16)(acc[mi][j][r] + bv);
            }
        }
    } else {
        float* o = (float*)out;
#pragma unroll
        for (int mi = 0; mi < 8; mi++) {
            const int nb = m0 + wm * 128 + mi * 16 + fq4;
            const int bI = nb >> 10, hw = nb & 1023;
#pragma unroll
            for (int j = 0; j < 3; j++) {
                const int col = n0 + wn * 48 + j * 16 + fr;
                f32x4 v = acc[mi][j] + bias[col];
                *(f32x4*)(o + ((size_t)bI * DIM + col) * HW + hw) = v;
            }
        }
    }
}

// ---------------- LayerNorm + exact GELU, in-place on k-permuted bf16 rows ----------------
__global__ __launch_bounds__(256) void ln_gelu_kernel(
    bf16* __restrict__ h, const float* __restrict__ g, const float* __restrict__ beta)
{
    const int wave = threadIdx.x >> 6;
    const int lane = threadIdx.x & 63;
    const int n = blockIdx.x * 4 + wave;
    bf16* row = h + (size_t)n * DIM;

    float v[12];
    float s = 0.f, ss = 0.f;
#pragma unroll
    for (int j = 0; j < 3; j++) {
        bf16x4 x = *(const bf16x4*)(row + j * 256 + lane * 4);
#pragma unroll
        for (int i = 0; i < 4; i++) {
            float f = (float)x[i];
            v[j * 4 + i] = f;
            s += f;
            ss += f * f;
        }
    }
#pragma unroll
    for (int off = 32; off > 0; off >>= 1) {
        s += __shfl_xor(s, off);
        ss += __shfl_xor(ss, off);
    }
    const float mu = s * (1.f / DIM);
    const float var = ss * (1.f / DIM) - mu * mu;
    const float rstd = rsqrtf(var + 1e-6f);

#pragma unroll
    for (int j = 0; j < 3; j++) {
        bf16x4 r;
#pragma unroll
        for (int i = 0; i < 4; i++) {
            const int c = j * 256 + lane * 4 + i;   // physical position
            const int p = (lane * 4 + i) & 31;
            const int kk = ((p >> 3) << 2) + (p & 7) + ((p & 4) ? 12 : 0);  // pos2k
            const int gi = (c & ~31) + kk;          // logical channel for gamma/beta
            float y = (v[j * 4 + i] - mu) * rstd * g[gi] + beta[gi];
            y = 0.5f * y * (1.f + erff(y * 0.70710678118f));
            r[i] = (bf16)y;
        }
        *(bf16x4*)(row + j * 256 + lane * 4) = r;
    }
}

extern "C" void kernel_launch(void* const* d_in, const int* in_sizes, int n_in,
                              void* d_out, int out_size, void* d_ws, size_t ws_size,
                              hipStream_t stream) {
    const float* x   = (const float*)d_in[0];
    const float* W1  = (const float*)d_in[1];
    const float* b1  = (const float*)d_in[2];
    const float* g1  = (const float*)d_in[3];
    const float* be1 = (const float*)d_in[4];
    const float* W2  = (const float*)d_in[5];
    const float* b2  = (const float*)d_in[6];
    const float* g2  = (const float*)d_in[7];
    const float* be2 = (const float*)d_in[8];
    const float* W3  = (const float*)d_in[9];
    const float* b3  = (const float*)d_in[10];
    float* out = (float*)d_out;

    bf16* Wb1  = (bf16*)d_ws;
    bf16* Wb2  = Wb1 + (size_t)DIM * DIM;
    bf16* Wb3  = Wb2 + (size_t)DIM * DIM;
    bf16* buf0 = Wb3 + (size_t)DIM * DIM;          // 16384*768 bf16
    bf16* buf1 = buf0 + (size_t)M_TOTAL * DIM;

    // weights -> bf16 k-permuted + x NCHW -> [n][c] bf16 k-permuted (one launch)
    prep_kernel<<<864 + 12288, 256, 0, stream>>>(
        x, buf0, (const float4*)W1, (const float4*)W2, (const float4*)W3,
        (bf16x8*)Wb1, (bf16x8*)Wb2, (bf16x8*)Wb3);

    const int ggrid = (M_TOTAL / 256) * (DIM / 192);   // 64*4 = 256 = 1/CU, all CUs
    // layer 1
    gemm_kernel<0><<<ggrid, 512, 0, stream>>>(buf0, Wb1, b1, buf1);
    ln_gelu_kernel<<<M_TOTAL / 4, 256, 0, stream>>>(buf1, g1, be1);
    // layer 2
    gemm_kernel<0><<<ggrid, 512, 0, stream>>>(buf1, Wb2, b2, buf0);
    ln_gelu_kernel<<<M_TOTAL / 4, 256, 0, stream>>>(buf0, g2, be2);
    // layer 3 -> NCHW f32 output
    gemm_kernel<1><<<ggrid, 512, 0, stream>>>(buf0, Wb3, b3, out);
}

// Round 14
// 141.668 us; speedup vs baseline: 3.0185x; 1.0031x over previous
//
#include <hip/hip_runtime.h>
#include <hip/hip_bf16.h>

typedef __bf16 bf16;
typedef __bf16 bf16x4 __attribute__((ext_vector_type(4)));
typedef __bf16 bf16x8 __attribute__((ext_vector_type(8)));
typedef float f32x4 __attribute__((ext_vector_type(4)));

#define DIM 768
#define HW 1024          // 32*32
#define BATCH 16
#define M_TOTAL (BATCH * HW)   // 16384
#define NKT 12                 // K-tiles of 64

#define AS1 __attribute__((address_space(1)))
#define AS3 __attribute__((address_space(3)))

// ======================== k-permutation convention =========================
// All bf16 [.][768] activation buffers and Wb[768][768] store the k (channel)
// dimension permuted within each 32-group: physical position p = 8g+j holds
// logical k = 4g+j (j<4) or 16+4g+(j-4) (j>=4). mfma_f32_16x16x32_bf16
// fragments are then CONTIGUOUS 16B in LDS -> single ds_read_b128 per
// fragment. k2pos(kk) = (((kk&15)>>2)<<3)+(kk&3)+((kk>>4)<<2). (validated R4-R13)

// ------------- prep: weights f32->bf16 k-permuted + x NCHW -> [n][c] bf16 -------------
__global__ void prep_kernel(const float* __restrict__ x, bf16* __restrict__ xb,
                            const float4* __restrict__ w1, const float4* __restrict__ w2,
                            const float4* __restrict__ w3,
                            bf16x8* __restrict__ o1, bf16x8* __restrict__ o2,
                            bf16x8* __restrict__ o3) {
    __shared__ float tile[32][33];
    if (blockIdx.x < 864) {
        const int b = blockIdx.x;
        const int which = b / 288;
        const int i = (b % 288) * 256 + threadIdx.x;
        const float4* w = which == 0 ? w1 : which == 1 ? w2 : w3;
        bf16x8* o = which == 0 ? o1 : which == 1 ? o2 : o3;
        const int row = i / 96, br = i % 96;
        const int q = br >> 2, g = br & 3;
        float4 lo = w[row * 192 + q * 8 + g];
        float4 hi = w[row * 192 + q * 8 + g + 4];
        bf16x8 r = { (bf16)lo.x, (bf16)lo.y, (bf16)lo.z, (bf16)lo.w,
                     (bf16)hi.x, (bf16)hi.y, (bf16)hi.z, (bf16)hi.w };
        o[row * 96 + br] = r;
    } else {
        const int e = blockIdx.x - 864;
        const int b = e / 768;
        const int rem = e % 768;
        const int c0 = (rem / 32) * 32;
        const int hw0 = (rem % 32) * 32;
        const int tx = threadIdx.x & 31, ty = threadIdx.x >> 5;  // 32 x 8

        const float* src = x + ((size_t)b * DIM + c0) * HW + hw0;
#pragma unroll
        for (int j = 0; j < 4; j++)
            tile[ty + 8 * j][tx] = src[(size_t)(ty + 8 * j) * HW + tx];
        __syncthreads();
        const int ptx = (((tx & 15) >> 2) << 3) + (tx & 3) + ((tx >> 4) << 2);  // k2pos
        bf16* dst = xb + ((size_t)b * HW + hw0) * DIM + c0;
#pragma unroll
        for (int j = 0; j < 4; j++)
            dst[(size_t)(ty + 8 * j) * DIM + ptx] = (bf16)tile[tx][ty + 8 * j];
    }
}

// ---------------- GEMM: 256x192 tile, BK=64, 8 waves (2x4), free-running ----------------
// grid 256 = every CU busy. R14 changes vs R13:
//  (a) NO manual lgkm waits after frag-read clusters -- the compiler's own
//      fine-grained lgkmcnt insertion overlaps P2 ds_reads with P1 MFMAs;
//      the only manual lgkmcnt(0) sits right before hazard barrier (i).
//  (b) all 22 ds_reads of the K-tile issued up front (a[] mh0, a2[] mh1).
//  (c) all 5 remaining kt+1 stage chunks issued in P1 -> vmcnt(2) at the
//      K-tile end has a full tile of cover. Outstanding at wait = kt+2 A0,A1.
// MODE 0: write bf16 [n][768] k-permuted (+bias). MODE 1: write f32 NCHW (+bias).
template <int MODE>
__global__ __launch_bounds__(512, 2) void gemm_kernel(
    const bf16* __restrict__ A,   // [M][768] k-permuted
    const bf16* __restrict__ Bw,  // [768][768] rows linear, cols k-permuted
    const float* __restrict__ bias,
    void* __restrict__ out)
{
    constexpr int K = DIM;
    __shared__ bf16 ldsA[2][256][64];   // 64 KiB
    __shared__ bf16 ldsB[2][192][64];   // 48 KiB

    const int t = threadIdx.x;
    const int lane = t & 63;
    const int wave = t >> 6;
    const int wm = wave >> 2, wn = wave & 3;   // 2 x 4 -> wave tile 128 x 48

    const int bid = blockIdx.x;                 // 256 blocks, 256%8==0
    const int virt = (bid & 7) * 32 + (bid >> 3);
    const int m0 = (virt >> 2) * 256;           // 64 m-tiles
    const int n0 = (virt & 3) * 192;            // 4 n-tiles (n fastest: share A)

    const int fr = lane & 15;
    const int fq = lane >> 4;

    f32x4 acc[8][3] = {};

    const int s_r = t >> 3;     // 0..63, staging row within chunk
    const int s_blk = t & 7;    // staging 16B block in row

    // chunk c: 0..3 = A rows c*64.., 4..6 = B rows (c-4)*64..
    auto stage_chunk = [&](int kt, int c) {
        const int d = kt & 1;
        if (c < 4) {
            const int r = c * 64 + s_r;
            __builtin_amdgcn_global_load_lds(
                (const AS1 void*)(A + (size_t)(m0 + r) * K + kt * 64 + ((s_blk ^ (r & 7)) << 3)),
                (AS3 void*)&ldsA[d][r][s_blk * 8], 16, 0, 0);
        } else {
            const int r = (c - 4) * 64 + s_r;
            __builtin_amdgcn_global_load_lds(
                (const AS1 void*)(Bw + (size_t)(n0 + r) * K + kt * 64 + ((s_blk ^ (r & 7)) << 3)),
                (AS3 void*)&ldsB[d][r][s_blk * 8], 16, 0, 0);
        }
    };

    bf16x8 a[8], a2[8], b[6];

    auto ldA = [&](bf16x8* dst, int kt, int mh) {   // 8 x ds_read_b128
        const int d = kt & 1;
#pragma unroll
        for (int mi = 0; mi < 4; mi++) {
            const int R = wm * 128 + (mh * 4 + mi) * 16 + fr;
            const bf16* rp = &ldsA[d][R][0];
            const int s = R & 7;
#pragma unroll
            for (int ks = 0; ks < 2; ks++)
                dst[mi * 2 + ks] = *(const bf16x8*)(rp + (((ks * 4 + fq) ^ s) << 3));
        }
    };
    auto ldB = [&](int kt) {           // 6 x ds_read_b128 (all 3 n-frags)
        const int d = kt & 1;
#pragma unroll
        for (int j = 0; j < 3; j++) {
            const int R = wn * 48 + j * 16 + fr;
            const bf16* rp = &ldsB[d][R][0];
            const int s = R & 7;
#pragma unroll
            for (int ks = 0; ks < 2; ks++)
                b[j * 2 + ks] = *(const bf16x8*)(rp + (((ks * 4 + fq) ^ s) << 3));
        }
    };
    // MFMA cluster: half-row frags `src`, n-frags [j0, j1)
    auto MM = [&](const bf16x8* src, int mh, int j0, int j1) {
        __builtin_amdgcn_s_setprio(1);
#pragma unroll
        for (int mi = 0; mi < 4; mi++)
#pragma unroll
            for (int j = 0; j < 3; j++)
                if (j >= j0 && j < j1)
#pragma unroll
                    for (int ks = 0; ks < 2; ks++)
                        acc[mh * 4 + mi][j] = __builtin_amdgcn_mfma_f32_16x16x32_bf16(
                            src[mi * 2 + ks], b[j * 2 + ks], acc[mh * 4 + mi][j], 0, 0, 0);
        __builtin_amdgcn_s_setprio(0);
    };

    // prologue: kt0 all 7 chunks + kt1 A0,A1 -> vmcnt(2): kt0 resident
#pragma unroll
    for (int c = 0; c < 7; c++) stage_chunk(0, c);
    stage_chunk(1, 0); stage_chunk(1, 1);
    asm volatile("s_waitcnt vmcnt(2)" ::: "memory");
    __builtin_amdgcn_s_barrier();

    for (int kt = 0; kt < NKT; ++kt) {
        // issue every ds_read of this K-tile up front; compiler inserts
        // fine-grained counted lgkm waits before each dependent MFMA.
        ldA(a, kt, 0);
        ldB(kt);
        ldA(a2, kt, 1);
        // stage ALL remaining kt+1 chunks now (max vmcnt cover)
        if (kt + 1 < NKT) {
            stage_chunk(kt + 1, 2); stage_chunk(kt + 1, 3); stage_chunk(kt + 1, 4);
            stage_chunk(kt + 1, 5); stage_chunk(kt + 1, 6);
        }
        MM(a, 0, 0, 3);                 // 24 MFMA (overlaps a2 ds_read latency)
        MM(a2, 1, 0, 2);                // 16 MFMA

        // hazard barrier (i): this wave's dbuf-d reads drained, then sync
        asm volatile("s_waitcnt lgkmcnt(0)" ::: "memory");
        __builtin_amdgcn_s_barrier();
        if (kt + 2 < NKT) { stage_chunk(kt + 2, 0); stage_chunk(kt + 2, 1); }  // into dbuf d
        MM(a2, 1, 2, 3);                // 8 MFMA (covers stage issue)

        // hazard barrier (ii): kt+1 resident for all waves before next iter
        if (kt < NKT - 2) {
            asm volatile("s_waitcnt vmcnt(2)" ::: "memory");
            __builtin_amdgcn_s_barrier();
        } else if (kt == NKT - 2) {
            asm volatile("s_waitcnt vmcnt(0)" ::: "memory");
            __builtin_amdgcn_s_barrier();
        }
        __builtin_amdgcn_sched_barrier(0);   // no next-iter ds_read hoists above barrier
    }

    // ---------------- epilogue ----------------
    const int fq4 = fq * 4;
    if (MODE == 0) {
        bf16* o = (bf16*)out;
#pragma unroll
        for (int mi = 0; mi < 8; mi++) {
            const int row = m0 + wm * 128 + mi * 16 + fq4;
#pragma unroll
            for (int j = 0; j < 3; j++) {
                const int gcol = n0 + wn * 48 + j * 16 + fr;   // logical channel
                const int kk = gcol & 31;
                const int pcol = (gcol & ~31) + (((kk & 15) >> 2) << 3) + (kk & 3)
                               + ((kk >> 4) << 2);             // k2pos
                const float bv = bias[gcol];
#pragma unroll
                for (int r = 0; r < 4; r++)
                    o[(size_t)(row + r) * DIM + pcol] = (bf16)(acc[mi][j][r] + bv);
            }
        }
    } else {
        float* o = (float*)out;
#pragma unroll
        for (int mi = 0; mi < 8; mi++) {
            const int nb = m0 + wm * 128 + mi * 16 + fq4;
            const int bI = nb >> 10, hw = nb & 1023;
#pragma unroll
            for (int j = 0; j < 3; j++) {
                const int col = n0 + wn * 48 + j * 16 + fr;
                f32x4 v = acc[mi][j] + bias[col];
                *(f32x4*)(o + ((size_t)bI * DIM + col) * HW + hw) = v;
            }
        }
    }
}

// ---------------- LayerNorm + exact GELU, in-place on k-permuted bf16 rows ----------------
__global__ __launch_bounds__(256) void ln_gelu_kernel(
    bf16* __restrict__ h, const float* __restrict__ g, const float* __restrict__ beta)
{
    const int wave = threadIdx.x >> 6;
    const int lane = threadIdx.x & 63;
    const int n = blockIdx.x * 4 + wave;
    bf16* row = h + (size_t)n * DIM;

    float v[12];
    float s = 0.f, ss = 0.f;
#pragma unroll
    for (int j = 0; j < 3; j++) {
        bf16x4 x = *(const bf16x4*)(row + j * 256 + lane * 4);
#pragma unroll
        for (int i = 0; i < 4; i++) {
            float f = (float)x[i];
            v[j * 4 + i] = f;
            s += f;
            ss += f * f;
        }
    }
#pragma unroll
    for (int off = 32; off > 0; off >>= 1) {
        s += __shfl_xor(s, off);
        ss += __shfl_xor(ss, off);
    }
    const float mu = s * (1.f / DIM);
    const float var = ss * (1.f / DIM) - mu * mu;
    const float rstd = rsqrtf(var + 1e-6f);

#pragma unroll
    for (int j = 0; j < 3; j++) {
        bf16x4 r;
#pragma unroll
        for (int i = 0; i < 4; i++) {
            const int c = j * 256 + lane * 4 + i;   // physical position
            const int p = (lane * 4 + i) & 31;
            const int kk = ((p >> 3) << 2) + (p & 7) + ((p & 4) ? 12 : 0);  // pos2k
            const int gi = (c & ~31) + kk;          // logical channel for gamma/beta
            float y = (v[j * 4 + i] - mu) * rstd * g[gi] + beta[gi];
            y = 0.5f * y * (1.f + erff(y * 0.70710678118f));
            r[i] = (bf16)y;
        }
        *(bf16x4*)(row + j * 256 + lane * 4) = r;
    }
}

extern "C" void kernel_launch(void* const* d_in, const int* in_sizes, int n_in,
                              void* d_out, int out_size, void* d_ws, size_t ws_size,
                              hipStream_t stream) {
    const float* x   = (const float*)d_in[0];
    const float* W1  = (const float*)d_in[1];
    const float* b1  = (const float*)d_in[2];
    const float* g1  = (const float*)d_in[3];
    const float* be1 = (const float*)d_in[4];
    const float* W2  = (const float*)d_in[5];
    const float* b2  = (const float*)d_in[6];
    const float* g2  = (const float*)d_in[7];
    const float* be2 = (const float*)d_in[8];
    const float* W3  = (const float*)d_in[9];
    const float* b3  = (const float*)d_in[10];
    float* out = (float*)d_out;

    bf16* Wb1  = (bf16*)d_ws;
    bf16* Wb2  = Wb1 + (size_t)DIM * DIM;
    bf16* Wb3  = Wb2 + (size_t)DIM * DIM;
    bf16* buf0 = Wb3 + (size_t)DIM * DIM;          // 16384*768 bf16
    bf16* buf1 = buf0 + (size_t)M_TOTAL * DIM;

    // weights -> bf16 k-permuted + x NCHW -> [n][c] bf16 k-permuted (one launch)
    prep_kernel<<<864 + 12288, 256, 0, stream>>>(
        x, buf0, (const float4*)W1, (const float4*)W2, (const float4*)W3,
        (bf16x8*)Wb1, (bf16x8*)Wb2, (bf16x8*)Wb3);

    const int ggrid = (M_TOTAL / 256) * (DIM / 192);   // 64*4 = 256 = 1/CU, all CUs
    // layer 1
    gemm_kernel<0><<<ggrid, 512, 0, stream>>>(buf0, Wb1, b1, buf1);
    ln_gelu_kernel<<<M_TOTAL / 4, 256, 0, stream>>>(buf1, g1, be1);
    // layer 2
    gemm_kernel<0><<<ggrid, 512, 0, stream>>>(buf1, Wb2, b2, buf0);
    ln_gelu_kernel<<<M_TOTAL / 4, 256, 0, stream>>>(buf0, g2, be2);
    // layer 3 -> NCHW f32 output
    gemm_kernel<1><<<ggrid, 512, 0, stream>>>(buf0, Wb3, b3, out);
}

// Round 15
// 141.220 us; speedup vs baseline: 3.0281x; 1.0032x over previous
//
#include <hip/hip_runtime.h>
#include <hip/hip_bf16.h>

typedef __bf16 bf16;
typedef __bf16 bf16x4 __attribute__((ext_vector_type(4)));
typedef __bf16 bf16x8 __attribute__((ext_vector_type(8)));
typedef float f32x4 __attribute__((ext_vector_type(4)));

#define DIM 768
#define HW 1024          // 32*32
#define BATCH 16
#define M_TOTAL (BATCH * HW)   // 16384
#define NKT 12                 // K-tiles of 64

#define AS1 __attribute__((address_space(1)))
#define AS3 __attribute__((address_space(3)))

// ======================== k-permutation convention =========================
// All bf16 [.][768] activation buffers and Wb[768][768] store the k (channel)
// dimension permuted within each 32-group: physical position p = 8g+j holds
// logical k = 4g+j (j<4) or 16+4g+(j-4) (j>=4). mfma_f32_16x16x32_bf16
// fragments are then CONTIGUOUS 16B in LDS -> single ds_read_b128 per
// fragment. k2pos(kk) = (((kk&15)>>2)<<3)+(kk&3)+((kk>>4)<<2). (validated R4-R14)

// ------------- prep: weights f32->bf16 k-permuted + x NCHW -> [n][c] bf16 -------------
__global__ void prep_kernel(const float* __restrict__ x, bf16* __restrict__ xb,
                            const float4* __restrict__ w1, const float4* __restrict__ w2,
                            const float4* __restrict__ w3,
                            bf16x8* __restrict__ o1, bf16x8* __restrict__ o2,
                            bf16x8* __restrict__ o3) {
    __shared__ float tile[32][33];
    if (blockIdx.x < 864) {
        const int b = blockIdx.x;
        const int which = b / 288;
        const int i = (b % 288) * 256 + threadIdx.x;
        const float4* w = which == 0 ? w1 : which == 1 ? w2 : w3;
        bf16x8* o = which == 0 ? o1 : which == 1 ? o2 : o3;
        const int row = i / 96, br = i % 96;
        const int q = br >> 2, g = br & 3;
        float4 lo = w[row * 192 + q * 8 + g];
        float4 hi = w[row * 192 + q * 8 + g + 4];
        bf16x8 r = { (bf16)lo.x, (bf16)lo.y, (bf16)lo.z, (bf16)lo.w,
                     (bf16)hi.x, (bf16)hi.y, (bf16)hi.z, (bf16)hi.w };
        o[row * 96 + br] = r;
    } else {
        const int e = blockIdx.x - 864;
        const int b = e / 768;
        const int rem = e % 768;
        const int c0 = (rem / 32) * 32;
        const int hw0 = (rem % 32) * 32;
        const int tx = threadIdx.x & 31, ty = threadIdx.x >> 5;  // 32 x 8

        const float* src = x + ((size_t)b * DIM + c0) * HW + hw0;
#pragma unroll
        for (int j = 0; j < 4; j++)
            tile[ty + 8 * j][tx] = src[(size_t)(ty + 8 * j) * HW + tx];
        __syncthreads();
        const int ptx = (((tx & 15) >> 2) << 3) + (tx & 3) + ((tx >> 4) << 2);  // k2pos
        bf16* dst = xb + ((size_t)b * HW + hw0) * DIM + c0;
#pragma unroll
        for (int j = 0; j < 4; j++)
            dst[(size_t)(ty + 8 * j) * DIM + ptx] = (bf16)tile[tx][ty + 8 * j];
    }
}

// ---------------- GEMM: 256x192 tile, BK=64, 8 waves (2x4), free-running ----------------
// grid 256 = every CU busy. K-loop = R14 verbatim (best measured).
// R15: MODE 1 epilogue bounces C^T through LDS -- ds_write_b128 (column frag =
// 4 contiguous rows) into [col][row] f32 tiles (row-len 260: lanes fr -> banks
// 4*fr%32, 2-way = free), read back row-major, store 1KB-contiguous NCHW.
// Fixes the measured 2x write amplification + 4x store-transaction count.
// MODE 0: write bf16 [n][768] k-permuted (+bias). MODE 1: write f32 NCHW (+bias).
template <int MODE>
__global__ __launch_bounds__(512, 2) void gemm_kernel(
    const bf16* __restrict__ A,   // [M][768] k-permuted
    const bf16* __restrict__ Bw,  // [768][768] rows linear, cols k-permuted
    const float* __restrict__ bias,
    void* __restrict__ out)
{
    constexpr int K = DIM;
    __shared__ __align__(16) char smem[114688];   // 112 KiB
    bf16 (*ldsA)[256][64] = (bf16(*)[256][64])smem;            // 64 KiB
    bf16 (*ldsB)[192][64] = (bf16(*)[192][64])(smem + 65536);  // 48 KiB

    const int t = threadIdx.x;
    const int lane = t & 63;
    const int wave = t >> 6;
    const int wm = wave >> 2, wn = wave & 3;   // 2 x 4 -> wave tile 128 x 48

    const int bid = blockIdx.x;                 // 256 blocks, 256%8==0
    const int virt = (bid & 7) * 32 + (bid >> 3);
    const int m0 = (virt >> 2) * 256;           // 64 m-tiles
    const int n0 = (virt & 3) * 192;            // 4 n-tiles (n fastest: share A)

    const int fr = lane & 15;
    const int fq = lane >> 4;

    f32x4 acc[8][3] = {};

    const int s_r = t >> 3;     // 0..63, staging row within chunk
    const int s_blk = t & 7;    // staging 16B block in row

    // chunk c: 0..3 = A rows c*64.., 4..6 = B rows (c-4)*64..
    auto stage_chunk = [&](int kt, int c) {
        const int d = kt & 1;
        if (c < 4) {
            const int r = c * 64 + s_r;
            __builtin_amdgcn_global_load_lds(
                (const AS1 void*)(A + (size_t)(m0 + r) * K + kt * 64 + ((s_blk ^ (r & 7)) << 3)),
                (AS3 void*)&ldsA[d][r][s_blk * 8], 16, 0, 0);
        } else {
            const int r = (c - 4) * 64 + s_r;
            __builtin_amdgcn_global_load_lds(
                (const AS1 void*)(Bw + (size_t)(n0 + r) * K + kt * 64 + ((s_blk ^ (r & 7)) << 3)),
                (AS3 void*)&ldsB[d][r][s_blk * 8], 16, 0, 0);
        }
    };

    bf16x8 a[8], a2[8], b[6];

    auto ldA = [&](bf16x8* dst, int kt, int mh) {   // 8 x ds_read_b128
        const int d = kt & 1;
#pragma unroll
        for (int mi = 0; mi < 4; mi++) {
            const int R = wm * 128 + (mh * 4 + mi) * 16 + fr;
            const bf16* rp = &ldsA[d][R][0];
            const int s = R & 7;
#pragma unroll
            for (int ks = 0; ks < 2; ks++)
                dst[mi * 2 + ks] = *(const bf16x8*)(rp + (((ks * 4 + fq) ^ s) << 3));
        }
    };
    auto ldB = [&](int kt) {           // 6 x ds_read_b128 (all 3 n-frags)
        const int d = kt & 1;
#pragma unroll
        for (int j = 0; j < 3; j++) {
            const int R = wn * 48 + j * 16 + fr;
            const bf16* rp = &ldsB[d][R][0];
            const int s = R & 7;
#pragma unroll
            for (int ks = 0; ks < 2; ks++)
                b[j * 2 + ks] = *(const bf16x8*)(rp + (((ks * 4 + fq) ^ s) << 3));
        }
    };
    // MFMA cluster: half-row frags `src`, n-frags [j0, j1)
    auto MM = [&](const bf16x8* src, int mh, int j0, int j1) {
        __builtin_amdgcn_s_setprio(1);
#pragma unroll
        for (int mi = 0; mi < 4; mi++)
#pragma unroll
            for (int j = 0; j < 3; j++)
                if (j >= j0 && j < j1)
#pragma unroll
                    for (int ks = 0; ks < 2; ks++)
                        acc[mh * 4 + mi][j] = __builtin_amdgcn_mfma_f32_16x16x32_bf16(
                            src[mi * 2 + ks], b[j * 2 + ks], acc[mh * 4 + mi][j], 0, 0, 0);
        __builtin_amdgcn_s_setprio(0);
    };

    // prologue: kt0 all 7 chunks + kt1 A0,A1 -> vmcnt(2): kt0 resident
#pragma unroll
    for (int c = 0; c < 7; c++) stage_chunk(0, c);
    stage_chunk(1, 0); stage_chunk(1, 1);
    asm volatile("s_waitcnt vmcnt(2)" ::: "memory");
    __builtin_amdgcn_s_barrier();

    for (int kt = 0; kt < NKT; ++kt) {
        // issue every ds_read of this K-tile up front; compiler inserts
        // fine-grained counted lgkm waits before each dependent MFMA.
        ldA(a, kt, 0);
        ldB(kt);
        ldA(a2, kt, 1);
        // stage ALL remaining kt+1 chunks now (max vmcnt cover)
        if (kt + 1 < NKT) {
            stage_chunk(kt + 1, 2); stage_chunk(kt + 1, 3); stage_chunk(kt + 1, 4);
            stage_chunk(kt + 1, 5); stage_chunk(kt + 1, 6);
        }
        MM(a, 0, 0, 3);                 // 24 MFMA (overlaps a2 ds_read latency)
        MM(a2, 1, 0, 2);                // 16 MFMA

        // hazard barrier (i): this wave's dbuf-d reads drained, then sync
        asm volatile("s_waitcnt lgkmcnt(0)" ::: "memory");
        __builtin_amdgcn_s_barrier();
        if (kt + 2 < NKT) { stage_chunk(kt + 2, 0); stage_chunk(kt + 2, 1); }  // into dbuf d
        MM(a2, 1, 2, 3);                // 8 MFMA (covers stage issue)

        // hazard barrier (ii): kt+1 resident for all waves before next iter
        if (kt < NKT - 2) {
            asm volatile("s_waitcnt vmcnt(2)" ::: "memory");
            __builtin_amdgcn_s_barrier();
        } else if (kt == NKT - 2) {
            asm volatile("s_waitcnt vmcnt(0)" ::: "memory");
            __builtin_amdgcn_s_barrier();
        }
        __builtin_amdgcn_sched_barrier(0);   // no next-iter ds_read hoists above barrier
    }

    // ---------------- epilogue ----------------
    const int fq4 = fq * 4;
    if (MODE == 0) {
        bf16* o = (bf16*)out;
#pragma unroll
        for (int mi = 0; mi < 8; mi++) {
            const int row = m0 + wm * 128 + mi * 16 + fq4;
#pragma unroll
            for (int j = 0; j < 3; j++) {
                const int gcol = n0 + wn * 48 + j * 16 + fr;   // logical channel
                const int kk = gcol & 31;
                const int pcol = (gcol & ~31) + (((kk & 15) >> 2) << 3) + (kk & 3)
                               + ((kk >> 4) << 2);             // k2pos
                const float bv = bias[gcol];
#pragma unroll
                for (int r = 0; r < 4; r++)
                    o[(size_t)(row + r) * DIM + pcol] = (bf16)(acc[mi][j][r] + bv);
            }
        }
    } else {
        // C^T LDS bounce (2 halves of 96 cols): eb[colh][row], row-len 260 f32.
        float* eb = (float*)smem;            // 96*260*4 = 99,840 B <= 112 KiB (dead)
        float* o = (float*)out;
        const int bI = m0 >> 10, hw0 = m0 & 1023;
        __builtin_amdgcn_s_barrier();        // all waves done reading ldsA/ldsB
#pragma unroll
        for (int h = 0; h < 2; ++h) {
            if ((wn >> 1) == h) {            // waves owning these 96 cols write
#pragma unroll
                for (int mi = 0; mi < 8; mi++) {
                    const int row = wm * 128 + mi * 16 + fq4;
#pragma unroll
                    for (int j = 0; j < 3; j++) {
                        const int colh = (wn & 1) * 48 + j * 16 + fr;
                        const int col = n0 + wn * 48 + j * 16 + fr;
                        f32x4 v = acc[mi][j] + bias[col];
                        *(f32x4*)&eb[colh * 260 + row] = v;   // ds_write_b128
                    }
                }
            }
            asm volatile("s_waitcnt lgkmcnt(0)" ::: "memory");
            __builtin_amdgcn_s_barrier();
            // read back row-major, store 1KB-contiguous NCHW (6144 16B units)
#pragma unroll
            for (int k = 0; k < 12; ++k) {
                const int u = k * 512 + t;
                const int c = u >> 6, blk = u & 63;
                f32x4 v = *(const f32x4*)&eb[c * 260 + blk * 4];
                *(f32x4*)&o[((size_t)bI * DIM + n0 + h * 96 + c) * HW + hw0 + blk * 4] = v;
            }
            if (h == 0) __builtin_amdgcn_s_barrier();  // reads consumed before h1 writes
        }
    }
}

// ---------------- LayerNorm + exact GELU, in-place on k-permuted bf16 rows ----------------
__global__ __launch_bounds__(256) void ln_gelu_kernel(
    bf16* __restrict__ h, const float* __restrict__ g, const float* __restrict__ beta)
{
    const int wave = threadIdx.x >> 6;
    const int lane = threadIdx.x & 63;
    const int n = blockIdx.x * 4 + wave;
    bf16* row = h + (size_t)n * DIM;

    float v[12];
    float s = 0.f, ss = 0.f;
#pragma unroll
    for (int j = 0; j < 3; j++) {
        bf16x4 x = *(const bf16x4*)(row + j * 256 + lane * 4);
#pragma unroll
        for (int i = 0; i < 4; i++) {
            float f = (float)x[i];
            v[j * 4 + i] = f;
            s += f;
            ss += f * f;
        }
    }
#pragma unroll
    for (int off = 32; off > 0; off >>= 1) {
        s += __shfl_xor(s, off);
        ss += __shfl_xor(ss, off);
    }
    const float mu = s * (1.f / DIM);
    const float var = ss * (1.f / DIM) - mu * mu;
    const float rstd = rsqrtf(var + 1e-6f);

#pragma unroll
    for (int j = 0; j < 3; j++) {
        bf16x4 r;
#pragma unroll
        for (int i = 0; i < 4; i++) {
            const int c = j * 256 + lane * 4 + i;   // physical position
            const int p = (lane * 4 + i) & 31;
            const int kk = ((p >> 3) << 2) + (p & 7) + ((p & 4) ? 12 : 0);  // pos2k
            const int gi = (c & ~31) + kk;          // logical channel for gamma/beta
            float y = (v[j * 4 + i] - mu) * rstd * g[gi] + beta[gi];
            y = 0.5f * y * (1.f + erff(y * 0.70710678118f));
            r[i] = (bf16)y;
        }
        *(bf16x4*)(row + j * 256 + lane * 4) = r;
    }
}

extern "C" void kernel_launch(void* const* d_in, const int* in_sizes, int n_in,
                              void* d_out, int out_size, void* d_ws, size_t ws_size,
                              hipStream_t stream) {
    const float* x   = (const float*)d_in[0];
    const float* W1  = (const float*)d_in[1];
    const float* b1  = (const float*)d_in[2];
    const float* g1  = (const float*)d_in[3];
    const float* be1 = (const float*)d_in[4];
    const float* W2  = (const float*)d_in[5];
    const float* b2  = (const float*)d_in[6];
    const float* g2  = (const float*)d_in[7];
    const float* be2 = (const float*)d_in[8];
    const float* W3  = (const float*)d_in[9];
    const float* b3  = (const float*)d_in[10];
    float* out = (float*)d_out;

    bf16* Wb1  = (bf16*)d_ws;
    bf16* Wb2  = Wb1 + (size_t)DIM * DIM;
    bf16* Wb3  = Wb2 + (size_t)DIM * DIM;
    bf16* buf0 = Wb3 + (size_t)DIM * DIM;          // 16384*768 bf16
    bf16* buf1 = buf0 + (size_t)M_TOTAL * DIM;

    // weights -> bf16 k-permuted + x NCHW -> [n][c] bf16 k-permuted (one launch)
    prep_kernel<<<864 + 12288, 256, 0, stream>>>(
        x, buf0, (const float4*)W1, (const float4*)W2, (const float4*)W3,
        (bf16x8*)Wb1, (bf16x8*)Wb2, (bf16x8*)Wb3);

    const int ggrid = (M_TOTAL / 256) * (DIM / 192);   // 64*4 = 256 = 1/CU, all CUs
    // layer 1
    gemm_kernel<0><<<ggrid, 512, 0, stream>>>(buf0, Wb1, b1, buf1);
    ln_gelu_kernel<<<M_TOTAL / 4, 256, 0, stream>>>(buf1, g1, be1);
    // layer 2
    gemm_kernel<0><<<ggrid, 512, 0, stream>>>(buf1, Wb2, b2, buf0);
    ln_gelu_kernel<<<M_TOTAL / 4, 256, 0, stream>>>(buf0, g2, be2);
    // layer 3 -> NCHW f32 output
    gemm_kernel<1><<<ggrid, 512, 0, stream>>>(buf0, Wb3, b3, out);
}

// Round 16
// 140.843 us; speedup vs baseline: 3.0362x; 1.0027x over previous
//
#include <hip/hip_runtime.h>
#include <hip/hip_bf16.h>

typedef __bf16 bf16;
typedef __bf16 bf16x4 __attribute__((ext_vector_type(4)));
typedef __bf16 bf16x8 __attribute__((ext_vector_type(8)));
typedef float f32x4 __attribute__((ext_vector_type(4)));

#define DIM 768
#define HW 1024          // 32*32
#define BATCH 16
#define M_TOTAL (BATCH * HW)   // 16384
#define NKT 12                 // K-tiles of 64

#define AS1 __attribute__((address_space(1)))
#define AS3 __attribute__((address_space(3)))

// ======================== k-permutation convention =========================
// All bf16 [.][768] activation buffers and Wb[768][768] store the k (channel)
// dimension permuted within each 32-group: physical position p = 8g+j holds
// logical k = 4g+j (j<4) or 16+4g+(j-4) (j>=4). mfma_f32_16x16x32_bf16
// fragments are then CONTIGUOUS 16B in LDS -> single ds_read_b128 per
// fragment. k2pos(kk) = (((kk&15)>>2)<<3)+(kk&3)+((kk>>4)<<2). (validated R4-R15)

// ------------- prep: weights f32->bf16 k-permuted + x NCHW -> [n][c] bf16 -------------
__global__ void prep_kernel(const float* __restrict__ x, bf16* __restrict__ xb,
                            const float4* __restrict__ w1, const float4* __restrict__ w2,
                            const float4* __restrict__ w3,
                            bf16x8* __restrict__ o1, bf16x8* __restrict__ o2,
                            bf16x8* __restrict__ o3) {
    __shared__ float tile[32][33];
    if (blockIdx.x < 864) {
        const int b = blockIdx.x;
        const int which = b / 288;
        const int i = (b % 288) * 256 + threadIdx.x;
        const float4* w = which == 0 ? w1 : which == 1 ? w2 : w3;
        bf16x8* o = which == 0 ? o1 : which == 1 ? o2 : o3;
        const int row = i / 96, br = i % 96;
        const int q = br >> 2, g = br & 3;
        float4 lo = w[row * 192 + q * 8 + g];
        float4 hi = w[row * 192 + q * 8 + g + 4];
        bf16x8 r = { (bf16)lo.x, (bf16)lo.y, (bf16)lo.z, (bf16)lo.w,
                     (bf16)hi.x, (bf16)hi.y, (bf16)hi.z, (bf16)hi.w };
        o[row * 96 + br] = r;
    } else {
        const int e = blockIdx.x - 864;
        const int b = e / 768;
        const int rem = e % 768;
        const int c0 = (rem / 32) * 32;
        const int hw0 = (rem % 32) * 32;
        const int tx = threadIdx.x & 31, ty = threadIdx.x >> 5;  // 32 x 8

        const float* src = x + ((size_t)b * DIM + c0) * HW + hw0;
#pragma unroll
        for (int j = 0; j < 4; j++)
            tile[ty + 8 * j][tx] = src[(size_t)(ty + 8 * j) * HW + tx];
        __syncthreads();
        const int ptx = (((tx & 15) >> 2) << 3) + (tx & 3) + ((tx >> 4) << 2);  // k2pos
        bf16* dst = xb + ((size_t)b * HW + hw0) * DIM + c0;
#pragma unroll
        for (int j = 0; j < 4; j++)
            dst[(size_t)(ty + 8 * j) * DIM + ptx] = (bf16)tile[tx][ty + 8 * j];
    }
}

// ---------------- GEMM: 128x192 tile, BK=64, 4 waves (2x2), 2 blocks/CU ----------------
// R16 lever: SAME 8 waves/CU as R14, but split into TWO independent barrier
// domains (2 co-resident blocks of 4 waves; LDS exactly 80 KB). One block's
// MFMA fills the other's barrier/vmcnt stalls (m114 co-scheduling).
// Free-running loop (R14): all 14 ds_reads up front, compiler inserts counted
// lgkm waits; 2 hazard barriers/K-tile; counted vmcnt(4) (= kt+2's A gloads).
// grid = 128 m-tiles x 4 n-tiles = 512 blocks = 2/CU.
// MODE 0: write bf16 [n][768] k-permuted (+bias). MODE 1: write f32 NCHW (+bias).
template <int MODE>
__global__ __launch_bounds__(256, 2) void gemm_kernel(
    const bf16* __restrict__ A,   // [M][768] k-permuted
    const bf16* __restrict__ Bw,  // [768][768] rows linear, cols k-permuted
    const float* __restrict__ bias,
    void* __restrict__ out)
{
    constexpr int K = DIM;
    __shared__ bf16 ldsA[2][128][64];   // 32 KiB
    __shared__ bf16 ldsB[2][192][64];   // 48 KiB  (total 80 KB -> 2 blocks/CU)

    const int t = threadIdx.x;
    const int lane = t & 63;
    const int wave = t >> 6;
    const int wm = wave >> 1, wn = wave & 1;   // 2 x 2 -> wave tile 64 x 96

    const int bid = blockIdx.x;                 // 512 blocks, 512%8==0
    const int virt = (bid & 7) * 64 + (bid >> 3);
    const int m0 = (virt >> 2) * 128;           // 128 m-tiles
    const int n0 = (virt & 3) * 192;            // 4 n-tiles (n fastest: share A)

    const int fr = lane & 15;
    const int fq = lane >> 4;

    f32x4 acc[4][6] = {};

    const int s_r = t >> 3;     // 0..31, staging row within half-chunk
    const int s_blk = t & 7;    // staging 16B block in row

    // chunk c: 0..1 = A rows c*64.., 2..4 = B rows (c-2)*64..  (2 gloads/thread)
    auto stage_chunk = [&](int kt, int c) {
        const int d = kt & 1;
#pragma unroll
        for (int j = 0; j < 2; j++) {
            const int rr = s_r + j * 32;
            if (c < 2) {
                const int r = c * 64 + rr;
                __builtin_amdgcn_global_load_lds(
                    (const AS1 void*)(A + (size_t)(m0 + r) * K + kt * 64 + ((s_blk ^ (r & 7)) << 3)),
                    (AS3 void*)&ldsA[d][r][s_blk * 8], 16, 0, 0);
            } else {
                const int r = (c - 2) * 64 + rr;
                __builtin_amdgcn_global_load_lds(
                    (const AS1 void*)(Bw + (size_t)(n0 + r) * K + kt * 64 + ((s_blk ^ (r & 7)) << 3)),
                    (AS3 void*)&ldsB[d][r][s_blk * 8], 16, 0, 0);
            }
        }
    };

    bf16x8 a[8], b[12];

    auto ldA = [&](int kt) {           // 8 x ds_read_b128 (4 m-frags)
        const int d = kt & 1;
#pragma unroll
        for (int mi = 0; mi < 4; mi++) {
            const int R = wm * 64 + mi * 16 + fr;
            const bf16* rp = &ldsA[d][R][0];
            const int s = R & 7;
#pragma unroll
            for (int ks = 0; ks < 2; ks++)
                a[mi * 2 + ks] = *(const bf16x8*)(rp + (((ks * 4 + fq) ^ s) << 3));
        }
    };
    auto ldB = [&](int kt) {           // 12 x ds_read_b128 (6 n-frags)
        const int d = kt & 1;
#pragma unroll
        for (int j = 0; j < 6; j++) {
            const int R = wn * 96 + j * 16 + fr;
            const bf16* rp = &ldsB[d][R][0];
            const int s = R & 7;
#pragma unroll
            for (int ks = 0; ks < 2; ks++)
                b[j * 2 + ks] = *(const bf16x8*)(rp + (((ks * 4 + fq) ^ s) << 3));
        }
    };
    // MFMA cluster over n-frags [j0, j1)
    auto MM = [&](int j0, int j1) {
        __builtin_amdgcn_s_setprio(1);
#pragma unroll
        for (int mi = 0; mi < 4; mi++)
#pragma unroll
            for (int j = 0; j < 6; j++)
                if (j >= j0 && j < j1)
#pragma unroll
                    for (int ks = 0; ks < 2; ks++)
                        acc[mi][j] = __builtin_amdgcn_mfma_f32_16x16x32_bf16(
                            a[mi * 2 + ks], b[j * 2 + ks], acc[mi][j], 0, 0, 0);
        __builtin_amdgcn_s_setprio(0);
    };

    // prologue: kt0 all 5 chunks + kt1 A0,A1 -> vmcnt(4): kt0 resident
#pragma unroll
    for (int c = 0; c < 5; c++) stage_chunk(0, c);
    stage_chunk(1, 0); stage_chunk(1, 1);
    asm volatile("s_waitcnt vmcnt(4)" ::: "memory");
    __builtin_amdgcn_s_barrier();

    for (int kt = 0; kt < NKT; ++kt) {
        // all ds_reads of this K-tile up front; compiler inserts counted lgkm waits
        ldA(kt);
        ldB(kt);
        // stage kt+1's B chunks now (full-tile vmcnt cover)
        if (kt + 1 < NKT) { stage_chunk(kt + 1, 2); stage_chunk(kt + 1, 3); stage_chunk(kt + 1, 4); }
        MM(0, 4);                       // 32 MFMA

        // hazard barrier (i): this wave's dbuf-d reads drained, then sync
        asm volatile("s_waitcnt lgkmcnt(0)" ::: "memory");
        __builtin_amdgcn_s_barrier();
        if (kt + 2 < NKT) { stage_chunk(kt + 2, 0); stage_chunk(kt + 2, 1); }  // into dbuf d
        MM(4, 6);                       // 16 MFMA (covers stage issue)

        // hazard barrier (ii): kt+1 resident for all waves before next iter
        if (kt < NKT - 2) {
            asm volatile("s_waitcnt vmcnt(4)" ::: "memory");
            __builtin_amdgcn_s_barrier();
        } else if (kt == NKT - 2) {
            asm volatile("s_waitcnt vmcnt(0)" ::: "memory");
            __builtin_amdgcn_s_barrier();
        }
        __builtin_amdgcn_sched_barrier(0);   // no next-iter ds_read hoists above barrier
    }

    // ---------------- epilogue ----------------
    const int fq4 = fq * 4;
    if (MODE == 0) {
        bf16* o = (bf16*)out;
#pragma unroll
        for (int mi = 0; mi < 4; mi++) {
            const int row = m0 + wm * 64 + mi * 16 + fq4;
#pragma unroll
            for (int j = 0; j < 6; j++) {
                const int gcol = n0 + wn * 96 + j * 16 + fr;   // logical channel
                const int kk = gcol & 31;
                const int pcol = (gcol & ~31) + (((kk & 15) >> 2) << 3) + (kk & 3)
                               + ((kk >> 4) << 2);             // k2pos
                const float bv = bias[gcol];
#pragma unroll
                for (int r = 0; r < 4; r++)
                    o[(size_t)(row + r) * DIM + pcol] = (bf16)(acc[mi][j][r] + bv);
            }
        }
    } else {
        float* o = (float*)out;
#pragma unroll
        for (int mi = 0; mi < 4; mi++) {
            const int nb = m0 + wm * 64 + mi * 16 + fq4;
            const int bI = nb >> 10, hw = nb & 1023;
#pragma unroll
            for (int j = 0; j < 6; j++) {
                const int col = n0 + wn * 96 + j * 16 + fr;
                f32x4 v = acc[mi][j] + bias[col];
                *(f32x4*)(o + ((size_t)bI * DIM + col) * HW + hw) = v;
            }
        }
    }
}

// ---------------- LayerNorm + exact GELU, in-place on k-permuted bf16 rows ----------------
__global__ __launch_bounds__(256) void ln_gelu_kernel(
    bf16* __restrict__ h, const float* __restrict__ g, const float* __restrict__ beta)
{
    const int wave = threadIdx.x >> 6;
    const int lane = threadIdx.x & 63;
    const int n = blockIdx.x * 4 + wave;
    bf16* row = h + (size_t)n * DIM;

    float v[12];
    float s = 0.f, ss = 0.f;
#pragma unroll
    for (int j = 0; j < 3; j++) {
        bf16x4 x = *(const bf16x4*)(row + j * 256 + lane * 4);
#pragma unroll
        for (int i = 0; i < 4; i++) {
            float f = (float)x[i];
            v[j * 4 + i] = f;
            s += f;
            ss += f * f;
        }
    }
#pragma unroll
    for (int off = 32; off > 0; off >>= 1) {
        s += __shfl_xor(s, off);
        ss += __shfl_xor(ss, off);
    }
    const float mu = s * (1.f / DIM);
    const float var = ss * (1.f / DIM) - mu * mu;
    const float rstd = rsqrtf(var + 1e-6f);

#pragma unroll
    for (int j = 0; j < 3; j++) {
        bf16x4 r;
#pragma unroll
        for (int i = 0; i < 4; i++) {
            const int c = j * 256 + lane * 4 + i;   // physical position
            const int p = (lane * 4 + i) & 31;
            const int kk = ((p >> 3) << 2) + (p & 7) + ((p & 4) ? 12 : 0);  // pos2k
            const int gi = (c & ~31) + kk;          // logical channel for gamma/beta
            float y = (v[j * 4 + i] - mu) * rstd * g[gi] + beta[gi];
            y = 0.5f * y * (1.f + erff(y * 0.70710678118f));
            r[i] = (bf16)y;
        }
        *(bf16x4*)(row + j * 256 + lane * 4) = r;
    }
}

extern "C" void kernel_launch(void* const* d_in, const int* in_sizes, int n_in,
                              void* d_out, int out_size, void* d_ws, size_t ws_size,
                              hipStream_t stream) {
    const float* x   = (const float*)d_in[0];
    const float* W1  = (const float*)d_in[1];
    const float* b1  = (const float*)d_in[2];
    const float* g1  = (const float*)d_in[3];
    const float* be1 = (const float*)d_in[4];
    const float* W2  = (const float*)d_in[5];
    const float* b2  = (const float*)d_in[6];
    const float* g2  = (const float*)d_in[7];
    const float* be2 = (const float*)d_in[8];
    const float* W3  = (const float*)d_in[9];
    const float* b3  = (const float*)d_in[10];
    float* out = (float*)d_out;

    bf16* Wb1  = (bf16*)d_ws;
    bf16* Wb2  = Wb1 + (size_t)DIM * DIM;
    bf16* Wb3  = Wb2 + (size_t)DIM * DIM;
    bf16* buf0 = Wb3 + (size_t)DIM * DIM;          // 16384*768 bf16
    bf16* buf1 = buf0 + (size_t)M_TOTAL * DIM;

    // weights -> bf16 k-permuted + x NCHW -> [n][c] bf16 k-permuted (one launch)
    prep_kernel<<<864 + 12288, 256, 0, stream>>>(
        x, buf0, (const float4*)W1, (const float4*)W2, (const float4*)W3,
        (bf16x8*)Wb1, (bf16x8*)Wb2, (bf16x8*)Wb3);

    const int ggrid = (M_TOTAL / 128) * (DIM / 192);   // 128*4 = 512 = 2/CU
    // layer 1
    gemm_kernel<0><<<ggrid, 256, 0, stream>>>(buf0, Wb1, b1, buf1);
    ln_gelu_kernel<<<M_TOTAL / 4, 256, 0, stream>>>(buf1, g1, be1);
    // layer 2
    gemm_kernel<0><<<ggrid, 256, 0, stream>>>(buf1, Wb2, b2, buf0);
    ln_gelu_kernel<<<M_TOTAL / 4, 256, 0, stream>>>(buf0, g2, be2);
    // layer 3 -> NCHW f32 output
    gemm_kernel<1><<<ggrid, 256, 0, stream>>>(buf0, Wb3, b3, out);
}